// Round 1
// baseline (6486.453 us; speedup 1.0000x reference)
//
#include <hip/hip_runtime.h>
#include <math.h>

typedef unsigned short u16;
typedef __attribute__((ext_vector_type(8))) u16 u16x8;
typedef __attribute__((ext_vector_type(8))) __bf16 bf16x8;
typedef __attribute__((ext_vector_type(4))) float f32x4;

#define D_MODEL 2048
#define SEQ 2048
#define BATCH 2
#define NH 16
#define HD 128
#define DFF 8192
#define ROWS (BATCH * SEQ)  // 4096

__device__ __forceinline__ u16 f2bf(float f) {
  union { float f; unsigned u; } v; v.f = f;
  unsigned r = v.u + 0x7FFFu + ((v.u >> 16) & 1u);
  return (u16)(r >> 16);
}
__device__ __forceinline__ float bf2f(u16 b) {
  union { unsigned u; float f; } v; v.u = ((unsigned)b) << 16;
  return v.f;
}

__device__ __forceinline__ f32x4 mfma16(u16x8 a, u16x8 b, f32x4 c) {
  return __builtin_amdgcn_mfma_f32_16x16x32_bf16(
      __builtin_bit_cast(bf16x8, a), __builtin_bit_cast(bf16x8, b), c, 0, 0, 0);
}

// ---------------- fp32 -> bf16 bulk cast ----------------
__global__ __launch_bounds__(256) void cast_kernel(const float* __restrict__ in,
                                                   u16* __restrict__ out, int n8) {
  int i = blockIdx.x * 256 + threadIdx.x;
  if (i >= n8) return;
  const float4* p = (const float4*)in + (size_t)i * 2;
  float4 a = p[0], b = p[1];
  u16x8 o;
  o[0] = f2bf(a.x); o[1] = f2bf(a.y); o[2] = f2bf(a.z); o[3] = f2bf(a.w);
  o[4] = f2bf(b.x); o[5] = f2bf(b.y); o[6] = f2bf(b.z); o[7] = f2bf(b.w);
  *((u16x8*)out + i) = o;
}

// ---------------- RMSNorm (fp32 in, bf16 out) ----------------
__global__ __launch_bounds__(256) void rmsnorm_kernel(const float* __restrict__ x,
                                                      const float* __restrict__ w,
                                                      u16* __restrict__ out) {
  __shared__ float red[4];
  int row = blockIdx.x, t = threadIdx.x;
  const float4* xr = (const float4*)(x + (size_t)row * D_MODEL);
  float4 a = xr[t * 2], b = xr[t * 2 + 1];
  float ss = a.x * a.x + a.y * a.y + a.z * a.z + a.w * a.w +
             b.x * b.x + b.y * b.y + b.z * b.z + b.w * b.w;
#pragma unroll
  for (int m = 1; m < 64; m <<= 1) ss += __shfl_xor(ss, m, 64);
  if ((t & 63) == 0) red[t >> 6] = ss;
  __syncthreads();
  float tot = red[0] + red[1] + red[2] + red[3];
  float sc = rsqrtf(tot * (1.0f / D_MODEL) + 1e-6f);
  const float4* wr = (const float4*)w;
  float4 wa = wr[t * 2], wb = wr[t * 2 + 1];
  u16x8 o;
  o[0] = f2bf(a.x * sc * wa.x); o[1] = f2bf(a.y * sc * wa.y);
  o[2] = f2bf(a.z * sc * wa.z); o[3] = f2bf(a.w * sc * wa.w);
  o[4] = f2bf(b.x * sc * wb.x); o[5] = f2bf(b.y * sc * wb.y);
  o[6] = f2bf(b.z * sc * wb.z); o[7] = f2bf(b.w * sc * wb.w);
  *((u16x8*)(out + (size_t)row * D_MODEL) + t) = o;
}

// ---------------- bf16 MFMA GEMM: C(MxN) = A(MxK) @ B(KxN) ----------------
// EPI: 0 = bf16 out, 1 = f32 out + fp32 residual, 2 = silu -> bf16 out
template <int EPI>
__global__ __launch_bounds__(256) void gemm_kernel(const u16* __restrict__ A,
                                                   const u16* __restrict__ B,
                                                   void* __restrict__ Cv,
                                                   const float* __restrict__ res,
                                                   int N, int K) {
  __shared__ u16 As[128 * 40];  // [row][k], stride 40 (80B, 16B-aligned, 2-way banks)
  __shared__ u16 Bs[128 * 40];  // transposed: [col][k]
  int tid = threadIdx.x, lane = tid & 63, wave = tid >> 6;
  int wm = wave >> 1, wn = wave & 1;
  int bm = blockIdx.y * 128, bn = blockIdx.x * 128;
  int r16 = lane & 15, kg = lane >> 4;
  f32x4 acc[4][4] = {};
  for (int k0 = 0; k0 < K; k0 += 32) {
    __syncthreads();
#pragma unroll
    for (int it = 0; it < 2; ++it) {
      int c = it * 256 + tid;  // 0..511
      int ar = c >> 2, ac = (c & 3) * 8;
      u16x8 av = *(const u16x8*)(A + (size_t)(bm + ar) * K + k0 + ac);
      *(u16x8*)(As + ar * 40 + ac) = av;
      int br = c >> 4, bc = (c & 15) * 8;
      u16x8 bv = *(const u16x8*)(B + (size_t)(k0 + br) * N + bn + bc);
#pragma unroll
      for (int j = 0; j < 8; ++j) Bs[(bc + j) * 40 + br] = bv[j];
    }
    __syncthreads();
    u16x8 af[4], bfr[4];
#pragma unroll
    for (int m = 0; m < 4; ++m)
      af[m] = *(const u16x8*)(As + (wm * 64 + m * 16 + r16) * 40 + kg * 8);
#pragma unroll
    for (int n = 0; n < 4; ++n)
      bfr[n] = *(const u16x8*)(Bs + (wn * 64 + n * 16 + r16) * 40 + kg * 8);
#pragma unroll
    for (int m = 0; m < 4; ++m)
#pragma unroll
      for (int n = 0; n < 4; ++n) acc[m][n] = mfma16(af[m], bfr[n], acc[m][n]);
  }
  // epilogue: D row = (lane>>4)*4 + reg, col = lane&15 (m89-verified layout)
#pragma unroll
  for (int m = 0; m < 4; ++m) {
    int r0 = bm + wm * 64 + m * 16 + kg * 4;
#pragma unroll
    for (int n = 0; n < 4; ++n) {
      int cc = bn + wn * 64 + n * 16 + r16;
#pragma unroll
      for (int r = 0; r < 4; ++r) {
        size_t idx = (size_t)(r0 + r) * N + cc;
        float v = acc[m][n][r];
        if (EPI == 1) {
          ((float*)Cv)[idx] = res[idx] + v;
        } else if (EPI == 0) {
          ((u16*)Cv)[idx] = f2bf(v);
        } else {
          float s = v / (1.0f + __expf(-v));
          ((u16*)Cv)[idx] = f2bf(s);
        }
      }
    }
  }
}

// ---------------- flash attention (fp32 math), 32 q-rows/block ----------------
// CAUSAL: apply causal mask. SELF: K/V (and Q) live in bf16 qkv buffer;
// else Q bf16 (B,T,H,d), K/V fp32 (B,T,GKV,d) with GQA h>>2.
template <bool CAUSAL, bool SELF>
__global__ __launch_bounds__(256) void attn_kernel(const u16* __restrict__ qp,
                                                   const void* __restrict__ kp,
                                                   const void* __restrict__ vp,
                                                   u16* __restrict__ outp) {
  __shared__ float Qs[32][132];
  __shared__ float Ks[32][132];
  __shared__ float Vs[32][132];
  __shared__ float Ps[32][36];
  int qt = blockIdx.x;
  int b = blockIdx.y >> 4, h = blockIdx.y & 15;
  int tid = threadIdx.x;
  int r = tid >> 3, sub = tid & 7, c = sub * 16;
  {  // stage Q tile (scaled by 1/sqrt(d))
    const u16* qb;
    size_t qstride;
    if (SELF) { qb = qp + (size_t)b * SEQ * 6144 + h * HD; qstride = 6144; }
    else      { qb = qp + ((size_t)b * SEQ * NH + h) * HD; qstride = (size_t)NH * HD; }
    const u16* src = qb + (size_t)(qt * 32 + r) * qstride + c;
    u16x8 qa = *(const u16x8*)src;
    u16x8 qc = *(const u16x8*)(src + 8);
    const float scale = 0.088388347648318447f;
#pragma unroll
    for (int i = 0; i < 8; ++i) {
      Qs[r][c + i] = bf2f(qa[i]) * scale;
      Qs[r][c + 8 + i] = bf2f(qc[i]) * scale;
    }
  }
  int qi = r;
  float m_run = -1e30f, l_run = 0.0f;
  float o[16] = {0};
  int ntiles = CAUSAL ? (qt + 1) : (SEQ / 32);
  for (int kt = 0; kt < ntiles; ++kt) {
    __syncthreads();  // protect prev-iter K/V/P reads
    if (SELF) {
      const u16* ks = (const u16*)kp + (size_t)(b * SEQ + kt * 32 + r) * 6144 + 2048 + h * HD + c;
      const u16* vs = ks + 2048;
      u16x8 k1 = *(const u16x8*)ks, k2 = *(const u16x8*)(ks + 8);
      u16x8 v1 = *(const u16x8*)vs, v2 = *(const u16x8*)(vs + 8);
#pragma unroll
      for (int i = 0; i < 8; ++i) {
        Ks[r][c + i] = bf2f(k1[i]); Ks[r][c + 8 + i] = bf2f(k2[i]);
        Vs[r][c + i] = bf2f(v1[i]); Vs[r][c + 8 + i] = bf2f(v2[i]);
      }
    } else {
      const float* ksf = (const float*)kp + ((size_t)(b * SEQ + kt * 32 + r) * 4 + (h >> 2)) * HD + c;
      const float* vsf = (const float*)vp + ((size_t)(b * SEQ + kt * 32 + r) * 4 + (h >> 2)) * HD + c;
#pragma unroll
      for (int i = 0; i < 4; ++i) {
        *(float4*)&Ks[r][c + i * 4] = *(const float4*)(ksf + i * 4);
        *(float4*)&Vs[r][c + i * 4] = *(const float4*)(vsf + i * 4);
      }
    }
    __syncthreads();
    float sc[4] = {0, 0, 0, 0};  // keys sub+8j
    for (int i4 = 0; i4 < HD; i4 += 4) {
      float4 qv = *(const float4*)&Qs[qi][i4];
#pragma unroll
      for (int j = 0; j < 4; ++j) {
        float4 kv = *(const float4*)&Ks[sub + 8 * j][i4];
        sc[j] += qv.x * kv.x + qv.y * kv.y + qv.z * kv.z + qv.w * kv.w;
      }
    }
    if (CAUSAL) {
      int qg = qt * 32 + qi;
#pragma unroll
      for (int j = 0; j < 4; ++j)
        if (kt * 32 + sub + 8 * j > qg) sc[j] = -1e30f;
    }
    float pm = fmaxf(fmaxf(sc[0], sc[1]), fmaxf(sc[2], sc[3]));
    pm = fmaxf(pm, __shfl_xor(pm, 1, 64));
    pm = fmaxf(pm, __shfl_xor(pm, 2, 64));
    pm = fmaxf(pm, __shfl_xor(pm, 4, 64));
    float m_new = fmaxf(m_run, pm);
    float corr = __expf(m_run - m_new);
    float psum = 0.0f;
#pragma unroll
    for (int j = 0; j < 4; ++j) {
      float p = __expf(sc[j] - m_new);
      Ps[qi][sub + 8 * j] = p;
      psum += p;
    }
    psum += __shfl_xor(psum, 1, 64);
    psum += __shfl_xor(psum, 2, 64);
    psum += __shfl_xor(psum, 4, 64);
    l_run = l_run * corr + psum;
    m_run = m_new;
#pragma unroll
    for (int i = 0; i < 16; ++i) o[i] *= corr;
    __syncthreads();  // P visible (uniform barrier: ntiles depends only on blockIdx)
    for (int k = 0; k < 32; ++k) {
      float p = Ps[qi][k];  // broadcast within 8-lane group
#pragma unroll
      for (int i = 0; i < 4; ++i) {  // cols sub*4 + i*32 (+0..3): conflict-free
        float4 vv = *(const float4*)&Vs[k][sub * 4 + i * 32];
        o[i * 4 + 0] += p * vv.x;
        o[i * 4 + 1] += p * vv.y;
        o[i * 4 + 2] += p * vv.z;
        o[i * 4 + 3] += p * vv.w;
      }
    }
  }
  float inv = 1.0f / l_run;
  u16* ob = outp + (size_t)(b * SEQ + qt * 32 + qi) * D_MODEL + h * HD;
#pragma unroll
  for (int i = 0; i < 4; ++i)
#pragma unroll
    for (int r2 = 0; r2 < 4; ++r2)
      ob[sub * 4 + i * 32 + r2] = f2bf(o[i * 4 + r2] * inv);
}

extern "C" void kernel_launch(void* const* d_in, const int* in_sizes, int n_in,
                              void* d_out, int out_size, void* d_ws, size_t ws_size,
                              hipStream_t stream) {
  const float* x          = (const float*)d_in[0];
  const float* k_ctx      = (const float*)d_in[1];
  const float* v_ctx      = (const float*)d_in[2];
  const float* wq         = (const float*)d_in[3];
  const float* wo_cross   = (const float*)d_in[4];
  const float* norm_q_w   = (const float*)d_in[5];
  const float* wqkv       = (const float*)d_in[6];
  const float* wo_self    = (const float*)d_in[7];
  const float* norm_qkv_w = (const float*)d_in[8];
  const float* ffn_w1     = (const float*)d_in[9];
  const float* ffn_w2     = (const float*)d_in[10];
  const float* ffn_norm_w = (const float*)d_in[11];
  float* out = (float*)d_out;

  char* ws = (char*)d_ws;
  size_t off = 0;
  auto alloc_u16 = [&](size_t n) { u16* p = (u16*)(ws + off); off += n * 2; return p; };
  auto alloc_f32 = [&](size_t n) { float* p = (float*)(ws + off); off += n * 4; return p; };
  u16* wq_bf   = alloc_u16((size_t)2048 * 2048);
  u16* woc_bf  = alloc_u16((size_t)2048 * 2048);
  u16* wqkv_bf = alloc_u16((size_t)2048 * 6144);
  u16* wos_bf  = alloc_u16((size_t)2048 * 2048);
  u16* w1_bf   = alloc_u16((size_t)2048 * 8192);
  u16* w2_bf   = alloc_u16((size_t)8192 * 2048);
  u16* xn_bf   = alloc_u16((size_t)ROWS * 2048);
  u16* qkv_bf  = alloc_u16((size_t)ROWS * 6144);  // also holds q (cross) & start of h1
  u16* attn_bf = alloc_u16((size_t)ROWS * 2048);  // ctx / ctx2 (bf16)
  float* x1    = alloc_f32((size_t)ROWS * 2048);
  float* x2    = alloc_f32((size_t)ROWS * 2048);
  u16* q_bf  = qkv_bf;
  u16* h1_bf = qkv_bf;  // qkv(25.2M u16)+attn(8.4M u16) = exactly 4096*8192 u16
  // total ws use: 256 MiB

  auto cast = [&](const float* src, u16* dst, size_t n) {
    int n8 = (int)(n / 8);
    cast_kernel<<<dim3((n8 + 255) / 256), dim3(256), 0, stream>>>(src, dst, n8);
  };
  cast(wq, wq_bf, (size_t)2048 * 2048);
  cast(wo_cross, woc_bf, (size_t)2048 * 2048);
  cast(wqkv, wqkv_bf, (size_t)2048 * 6144);
  cast(wo_self, wos_bf, (size_t)2048 * 2048);
  cast(ffn_w1, w1_bf, (size_t)2048 * 8192);
  cast(ffn_w2, w2_bf, (size_t)8192 * 2048);

  // ---- cross attention (GQA) ----
  rmsnorm_kernel<<<ROWS, 256, 0, stream>>>(x, norm_q_w, xn_bf);
  gemm_kernel<0><<<dim3(2048 / 128, ROWS / 128), 256, 0, stream>>>(
      xn_bf, wq_bf, q_bf, nullptr, 2048, 2048);
  attn_kernel<false, false><<<dim3(SEQ / 32, BATCH * NH), 256, 0, stream>>>(
      q_bf, k_ctx, v_ctx, attn_bf);
  gemm_kernel<1><<<dim3(2048 / 128, ROWS / 128), 256, 0, stream>>>(
      attn_bf, woc_bf, x1, x, 2048, 2048);

  // ---- causal self attention ----
  rmsnorm_kernel<<<ROWS, 256, 0, stream>>>(x1, norm_qkv_w, xn_bf);
  gemm_kernel<0><<<dim3(6144 / 128, ROWS / 128), 256, 0, stream>>>(
      xn_bf, wqkv_bf, qkv_bf, nullptr, 6144, 2048);
  attn_kernel<true, true><<<dim3(SEQ / 32, BATCH * NH), 256, 0, stream>>>(
      qkv_bf, qkv_bf, qkv_bf, attn_bf);
  gemm_kernel<1><<<dim3(2048 / 128, ROWS / 128), 256, 0, stream>>>(
      attn_bf, wos_bf, x2, x1, 2048, 2048);

  // ---- FFN (SiLU) ----
  rmsnorm_kernel<<<ROWS, 256, 0, stream>>>(x2, ffn_norm_w, xn_bf);
  gemm_kernel<2><<<dim3(8192 / 128, ROWS / 128), 256, 0, stream>>>(
      xn_bf, w1_bf, h1_bf, nullptr, 8192, 2048);
  gemm_kernel<1><<<dim3(2048 / 128, ROWS / 128), 256, 0, stream>>>(
      h1_bf, w2_bf, out, x2, 2048, 8192);
}

// Round 3
// 3117.787 us; speedup vs baseline: 2.0805x; 2.0805x over previous
//
#include <hip/hip_runtime.h>
#include <math.h>

typedef unsigned short u16;
typedef __attribute__((ext_vector_type(8))) u16 u16x8;
typedef __attribute__((ext_vector_type(8))) __bf16 bf16x8;
typedef __attribute__((ext_vector_type(4))) float f32x4;

#define D_MODEL 2048
#define SEQ 2048
#define BATCH 2
#define NH 16
#define HD 128
#define DFF 8192
#define ROWS (BATCH * SEQ)  // 4096

__device__ __forceinline__ u16 f2bf(float f) {
  union { float f; unsigned u; } v; v.f = f;
  unsigned r = v.u + 0x7FFFu + ((v.u >> 16) & 1u);
  return (u16)(r >> 16);
}
__device__ __forceinline__ float bf2f(u16 b) {
  union { unsigned u; float f; } v; v.u = ((unsigned)b) << 16;
  return v.f;
}

__device__ __forceinline__ f32x4 mfma16(u16x8 a, u16x8 b, f32x4 c) {
  return __builtin_amdgcn_mfma_f32_16x16x32_bf16(
      __builtin_bit_cast(bf16x8, a), __builtin_bit_cast(bf16x8, b), c, 0, 0, 0);
}

// ---------------- fp32 -> bf16 bulk cast ----------------
__global__ __launch_bounds__(256) void cast_kernel(const float* __restrict__ in,
                                                   u16* __restrict__ out, int n8) {
  int i = blockIdx.x * 256 + threadIdx.x;
  if (i >= n8) return;
  const float4* p = (const float4*)in + (size_t)i * 2;
  float4 a = p[0], b = p[1];
  u16x8 o;
  o[0] = f2bf(a.x); o[1] = f2bf(a.y); o[2] = f2bf(a.z); o[3] = f2bf(a.w);
  o[4] = f2bf(b.x); o[5] = f2bf(b.y); o[6] = f2bf(b.z); o[7] = f2bf(b.w);
  *((u16x8*)out + i) = o;
}

// ---------------- RMSNorm (fp32 in, bf16 out) ----------------
__global__ __launch_bounds__(256) void rmsnorm_kernel(const float* __restrict__ x,
                                                      const float* __restrict__ w,
                                                      u16* __restrict__ out) {
  __shared__ float red[4];
  int row = blockIdx.x, t = threadIdx.x;
  const float4* xr = (const float4*)(x + (size_t)row * D_MODEL);
  float4 a = xr[t * 2], b = xr[t * 2 + 1];
  float ss = a.x * a.x + a.y * a.y + a.z * a.z + a.w * a.w +
             b.x * b.x + b.y * b.y + b.z * b.z + b.w * b.w;
#pragma unroll
  for (int m = 1; m < 64; m <<= 1) ss += __shfl_xor(ss, m, 64);
  if ((t & 63) == 0) red[t >> 6] = ss;
  __syncthreads();
  float tot = red[0] + red[1] + red[2] + red[3];
  float sc = rsqrtf(tot * (1.0f / D_MODEL) + 1e-6f);
  const float4* wr = (const float4*)w;
  float4 wa = wr[t * 2], wb = wr[t * 2 + 1];
  u16x8 o;
  o[0] = f2bf(a.x * sc * wa.x); o[1] = f2bf(a.y * sc * wa.y);
  o[2] = f2bf(a.z * sc * wa.z); o[3] = f2bf(a.w * sc * wa.w);
  o[4] = f2bf(b.x * sc * wb.x); o[5] = f2bf(b.y * sc * wb.y);
  o[6] = f2bf(b.z * sc * wb.z); o[7] = f2bf(b.w * sc * wb.w);
  *((u16x8*)(out + (size_t)row * D_MODEL) + t) = o;
}

// ---------------- bf16 MFMA GEMM: C(MxN) = A(MxK) @ B(KxN) ----------------
// EPI: 0 = bf16 out, 1 = f32 out + fp32 residual, 2 = silu -> bf16 out
template <int EPI>
__global__ __launch_bounds__(256) void gemm_kernel(const u16* __restrict__ A,
                                                   const u16* __restrict__ B,
                                                   void* __restrict__ Cv,
                                                   const float* __restrict__ res,
                                                   int N, int K) {
  __shared__ __align__(16) u16 As[128 * 40];  // [row][k], stride 40
  __shared__ __align__(16) u16 Bs[128 * 40];  // transposed: [col][k]
  int tid = threadIdx.x, lane = tid & 63, wave = tid >> 6;
  int wm = wave >> 1, wn = wave & 1;
  int bm = blockIdx.y * 128, bn = blockIdx.x * 128;
  int r16 = lane & 15, kg = lane >> 4;
  f32x4 acc[4][4] = {};
  for (int k0 = 0; k0 < K; k0 += 32) {
    __syncthreads();
#pragma unroll
    for (int it = 0; it < 2; ++it) {
      int c = it * 256 + tid;  // 0..511
      int ar = c >> 2, ac = (c & 3) * 8;
      u16x8 av = *(const u16x8*)(A + (size_t)(bm + ar) * K + k0 + ac);
      *(u16x8*)(As + ar * 40 + ac) = av;
      int br = c >> 4, bc = (c & 15) * 8;
      u16x8 bv = *(const u16x8*)(B + (size_t)(k0 + br) * N + bn + bc);
#pragma unroll
      for (int j = 0; j < 8; ++j) Bs[(bc + j) * 40 + br] = bv[j];
    }
    __syncthreads();
    u16x8 af[4], bfr[4];
#pragma unroll
    for (int m = 0; m < 4; ++m)
      af[m] = *(const u16x8*)(As + (wm * 64 + m * 16 + r16) * 40 + kg * 8);
#pragma unroll
    for (int n = 0; n < 4; ++n)
      bfr[n] = *(const u16x8*)(Bs + (wn * 64 + n * 16 + r16) * 40 + kg * 8);
#pragma unroll
    for (int m = 0; m < 4; ++m)
#pragma unroll
      for (int n = 0; n < 4; ++n) acc[m][n] = mfma16(af[m], bfr[n], acc[m][n]);
  }
#pragma unroll
  for (int m = 0; m < 4; ++m) {
    int r0 = bm + wm * 64 + m * 16 + kg * 4;
#pragma unroll
    for (int n = 0; n < 4; ++n) {
      int cc = bn + wn * 64 + n * 16 + r16;
#pragma unroll
      for (int r = 0; r < 4; ++r) {
        size_t idx = (size_t)(r0 + r) * N + cc;
        float v = acc[m][n][r];
        if (EPI == 1) {
          ((float*)Cv)[idx] = res[idx] + v;
        } else if (EPI == 0) {
          ((u16*)Cv)[idx] = f2bf(v);
        } else {
          float s = v / (1.0f + __expf(-v));
          ((u16*)Cv)[idx] = f2bf(s);
        }
      }
    }
  }
}

// ---------------- MFMA flash attention ----------------
// 4 waves/block, wave = 16 q-rows (QBLK=64), KVBLK=32.
// SELF: q/k/v from qkv buffer (stride 6144, k at +2048, v at +4096), CAUSAL mask.
// else: q from q_bf (stride 2048), k/v bf16 (B,T,GKV,HD) with GQA kv-head = h>>2.
// V staged TRANSPOSED in LDS (Vt[d][key], stride 40) — same scatter-store +
// contiguous-b128-read pattern as the (verified) GEMM Bs path. No tr_read.
template <bool CAUSAL, bool SELF>
__global__ __launch_bounds__(256) void attn_mfma_kernel(
    const u16* __restrict__ qp, const u16* __restrict__ kp,
    const u16* __restrict__ vp, u16* __restrict__ outp) {
  __shared__ __align__(16) u16 KsL[32 * 136];     // [key][d], pad 136
  __shared__ __align__(16) u16 Vt[128 * 40];      // [d][key], pad 40
  __shared__ __align__(16) u16 PsL[4][16 * 40];   // per-wave [qrow][key], pad 40
  const int tid = threadIdx.x, lane = tid & 63, wave = tid >> 6;
  const int qt = blockIdx.x, b = blockIdx.y >> 4, h = blockIdx.y & 15;
  const int q0 = qt * 64;
  const int r16 = lane & 15, g4 = lane >> 4;

  // Q A-fragments: lane holds Q[r16][ks*32 + g4*8 + j]
  const size_t qstr = SELF ? 6144 : 2048;
  const u16* qrow = qp + (size_t)(b * SEQ + q0 + wave * 16 + r16) * qstr + h * HD + g4 * 8;
  u16x8 aq[4];
#pragma unroll
  for (int ks = 0; ks < 4; ++ks) aq[ks] = *(const u16x8*)(qrow + ks * 32);

  f32x4 acc_o[8] = {};
  float m_run[4] = {-1e30f, -1e30f, -1e30f, -1e30f};
  float l_run[4] = {0.f, 0.f, 0.f, 0.f};
  const int wqmax = q0 + wave * 16 + 15;
  const int ntiles = CAUSAL ? (q0 + 64) / 32 : SEQ / 32;
  const float scale = 0.088388347648318447f;  // 1/sqrt(128)

  for (int kt = 0; kt < ntiles; ++kt) {
    __syncthreads();  // previous tile's compute done before restage
#pragma unroll
    for (int it = 0; it < 2; ++it) {
      int ch = it * 256 + tid;            // 0..511
      int row = ch >> 4, col = (ch & 15) * 8;
      int key = kt * 32 + row;
      const u16 *ksrc, *vsrc;
      if (SELF) {
        const u16* base = kp + (size_t)(b * SEQ + key) * 6144 + h * HD + col;
        ksrc = base + 2048;
        vsrc = base + 4096;
      } else {
        size_t o = ((size_t)(b * SEQ + key) * 4 + (h >> 2)) * HD + col;
        ksrc = kp + o; vsrc = vp + o;
      }
      u16x8 kv = *(const u16x8*)ksrc;
      u16x8 vv = *(const u16x8*)vsrc;
      *(u16x8*)(KsL + row * 136 + col) = kv;
#pragma unroll
      for (int j = 0; j < 8; ++j) Vt[(col + j) * 40 + row] = vv[j];
    }
    __syncthreads();
    if (CAUSAL && kt * 32 > wqmax) continue;  // fully-masked for this wave; barrier count uniform

    // ---- QK^T: S(16x32) ----
    f32x4 s[2] = {};
#pragma unroll
    for (int nb = 0; nb < 2; ++nb)
#pragma unroll
      for (int ks = 0; ks < 4; ++ks) {
        u16x8 kf = *(const u16x8*)(KsL + (nb * 16 + r16) * 136 + ks * 32 + g4 * 8);
        s[nb] = mfma16(aq[ks], kf, s[nb]);
      }

    // ---- online softmax (rows g4*4+rr, cols r16 / 16+r16) ----
    float p[2][4], corr[4];
#pragma unroll
    for (int rr = 0; rr < 4; ++rr) {
      float s0 = s[0][rr] * scale, s1 = s[1][rr] * scale;
      if (CAUSAL) {
        int qg = q0 + wave * 16 + g4 * 4 + rr;
        if (kt * 32 + r16 > qg) s0 = -1e30f;
        if (kt * 32 + 16 + r16 > qg) s1 = -1e30f;
      }
      float pm = fmaxf(s0, s1);
      pm = fmaxf(pm, __shfl_xor(pm, 1, 64));
      pm = fmaxf(pm, __shfl_xor(pm, 2, 64));
      pm = fmaxf(pm, __shfl_xor(pm, 4, 64));
      pm = fmaxf(pm, __shfl_xor(pm, 8, 64));
      float mn = fmaxf(m_run[rr], pm);
      corr[rr] = __expf(m_run[rr] - mn);
      m_run[rr] = mn;
      float p0 = __expf(s0 - mn), p1 = __expf(s1 - mn);
      p[0][rr] = p0; p[1][rr] = p1;
      float ps = p0 + p1;
      ps += __shfl_xor(ps, 1, 64);
      ps += __shfl_xor(ps, 2, 64);
      ps += __shfl_xor(ps, 4, 64);
      ps += __shfl_xor(ps, 8, 64);
      l_run[rr] = l_run[rr] * corr[rr] + ps;
    }

    // ---- P -> LDS (bf16, A-frag layout round-trip; wave-private, no barrier) ----
    u16* pw = PsL[wave];
#pragma unroll
    for (int rr = 0; rr < 4; ++rr) {
      int rowo = (g4 * 4 + rr) * 40;
      pw[rowo + r16] = f2bf(p[0][rr]);
      pw[rowo + 16 + r16] = f2bf(p[1][rr]);
    }
    // rescale O
#pragma unroll
    for (int s8 = 0; s8 < 8; ++s8)
#pragma unroll
      for (int rr = 0; rr < 4; ++rr) acc_o[s8][rr] *= corr[rr];

    u16x8 pa = *(const u16x8*)(pw + r16 * 40 + g4 * 8);

    // ---- PV: B-frag = contiguous read from transposed V ----
#pragma unroll
    for (int s8 = 0; s8 < 8; ++s8) {
      u16x8 vb = *(const u16x8*)(Vt + (s8 * 16 + r16) * 40 + g4 * 8);
      acc_o[s8] = mfma16(pa, vb, acc_o[s8]);
    }
  }

  // ---- epilogue ----
  u16* ob = outp + (size_t)(b * SEQ + q0 + wave * 16 + g4 * 4) * D_MODEL + h * HD + r16;
#pragma unroll
  for (int rr = 0; rr < 4; ++rr) {
    float inv = 1.0f / l_run[rr];
#pragma unroll
    for (int s8 = 0; s8 < 8; ++s8)
      ob[(size_t)rr * D_MODEL + s8 * 16] = f2bf(acc_o[s8][rr] * inv);
  }
}

extern "C" void kernel_launch(void* const* d_in, const int* in_sizes, int n_in,
                              void* d_out, int out_size, void* d_ws, size_t ws_size,
                              hipStream_t stream) {
  const float* x          = (const float*)d_in[0];
  const float* k_ctx      = (const float*)d_in[1];
  const float* v_ctx      = (const float*)d_in[2];
  const float* wq         = (const float*)d_in[3];
  const float* wo_cross   = (const float*)d_in[4];
  const float* norm_q_w   = (const float*)d_in[5];
  const float* wqkv       = (const float*)d_in[6];
  const float* wo_self    = (const float*)d_in[7];
  const float* norm_qkv_w = (const float*)d_in[8];
  const float* ffn_w1     = (const float*)d_in[9];
  const float* ffn_w2     = (const float*)d_in[10];
  const float* ffn_norm_w = (const float*)d_in[11];
  float* out = (float*)d_out;

  char* ws = (char*)d_ws;
  size_t off = 0;
  auto alloc_u16 = [&](size_t n) { u16* p = (u16*)(ws + off); off += n * 2; return p; };
  auto alloc_f32 = [&](size_t n) { float* p = (float*)(ws + off); off += n * 4; return p; };
  u16* wq_bf   = alloc_u16((size_t)2048 * 2048);
  u16* woc_bf  = alloc_u16((size_t)2048 * 2048);
  u16* wqkv_bf = alloc_u16((size_t)2048 * 6144);
  u16* wos_bf  = alloc_u16((size_t)2048 * 2048);
  u16* w1_bf   = alloc_u16((size_t)2048 * 8192);
  u16* w2_bf   = alloc_u16((size_t)8192 * 2048);
  u16* xn_bf   = alloc_u16((size_t)ROWS * 2048);
  u16* qkv_bf  = alloc_u16((size_t)ROWS * 6144);
  u16* attn_bf = alloc_u16((size_t)ROWS * 2048);
  float* x1    = alloc_f32((size_t)ROWS * 2048);
  float* x2    = alloc_f32((size_t)ROWS * 2048);
  u16* q_bf  = qkv_bf;
  u16* h1_bf = qkv_bf;                 // qkv + attn regions = 4096*8192 u16 for FFN hidden
  u16* kc_bf = (u16*)x2;               // x2 unused until self-attn output GEMM
  u16* vc_bf = kc_bf + (size_t)BATCH * SEQ * 4 * HD;

  auto cast = [&](const float* src, u16* dst, size_t n) {
    int n8 = (int)(n / 8);
    cast_kernel<<<dim3((n8 + 255) / 256), dim3(256), 0, stream>>>(src, dst, n8);
  };
  cast(wq, wq_bf, (size_t)2048 * 2048);
  cast(wo_cross, woc_bf, (size_t)2048 * 2048);
  cast(wqkv, wqkv_bf, (size_t)2048 * 6144);
  cast(wo_self, wos_bf, (size_t)2048 * 2048);
  cast(ffn_w1, w1_bf, (size_t)2048 * 8192);
  cast(ffn_w2, w2_bf, (size_t)8192 * 2048);
  cast(k_ctx, kc_bf, (size_t)BATCH * SEQ * 4 * HD);
  cast(v_ctx, vc_bf, (size_t)BATCH * SEQ * 4 * HD);

  // ---- cross attention (GQA) ----
  rmsnorm_kernel<<<ROWS, 256, 0, stream>>>(x, norm_q_w, xn_bf);
  gemm_kernel<0><<<dim3(2048 / 128, ROWS / 128), 256, 0, stream>>>(
      xn_bf, wq_bf, q_bf, nullptr, 2048, 2048);
  attn_mfma_kernel<false, false><<<dim3(SEQ / 64, BATCH * NH), 256, 0, stream>>>(
      q_bf, kc_bf, vc_bf, attn_bf);
  gemm_kernel<1><<<dim3(2048 / 128, ROWS / 128), 256, 0, stream>>>(
      attn_bf, woc_bf, x1, x, 2048, 2048);

  // ---- causal self attention ----
  rmsnorm_kernel<<<ROWS, 256, 0, stream>>>(x1, norm_qkv_w, xn_bf);
  gemm_kernel<0><<<dim3(6144 / 128, ROWS / 128), 256, 0, stream>>>(
      xn_bf, wqkv_bf, qkv_bf, nullptr, 6144, 2048);
  attn_mfma_kernel<true, true><<<dim3(SEQ / 64, BATCH * NH), 256, 0, stream>>>(
      qkv_bf, qkv_bf, qkv_bf, attn_bf);
  gemm_kernel<1><<<dim3(2048 / 128, ROWS / 128), 256, 0, stream>>>(
      attn_bf, wos_bf, x2, x1, 2048, 2048);

  // ---- FFN (SiLU) ----
  rmsnorm_kernel<<<ROWS, 256, 0, stream>>>(x2, ffn_norm_w, xn_bf);
  gemm_kernel<2><<<dim3(8192 / 128, ROWS / 128), 256, 0, stream>>>(
      xn_bf, w1_bf, h1_bf, nullptr, 8192, 2048);
  gemm_kernel<1><<<dim3(2048 / 128, ROWS / 128), 256, 0, stream>>>(
      h1_bf, w2_bf, out, x2, 2048, 8192);
}

// Round 4
// 1754.813 us; speedup vs baseline: 3.6964x; 1.7767x over previous
//
#include <hip/hip_runtime.h>
#include <math.h>

typedef unsigned short u16;
typedef __attribute__((ext_vector_type(8))) u16 u16x8;
typedef __attribute__((ext_vector_type(8))) __bf16 bf16x8;
typedef __attribute__((ext_vector_type(4))) float f32x4;

#define D_MODEL 2048
#define SEQ 2048
#define BATCH 2
#define NH 16
#define HD 128
#define DFF 8192
#define ROWS (BATCH * SEQ)  // 4096

__device__ __forceinline__ u16 f2bf(float f) {
  union { float f; unsigned u; } v; v.f = f;
  unsigned r = v.u + 0x7FFFu + ((v.u >> 16) & 1u);
  return (u16)(r >> 16);
}
__device__ __forceinline__ float bf2f(u16 b) {
  union { unsigned u; float f; } v; v.u = ((unsigned)b) << 16;
  return v.f;
}

__device__ __forceinline__ f32x4 mfma16(u16x8 a, u16x8 b, f32x4 c) {
  return __builtin_amdgcn_mfma_f32_16x16x32_bf16(
      __builtin_bit_cast(bf16x8, a), __builtin_bit_cast(bf16x8, b), c, 0, 0, 0);
}

__device__ __forceinline__ void gll16(const void* g, void* l) {
  __builtin_amdgcn_global_load_lds(
      (const __attribute__((address_space(1))) void*)g,
      (__attribute__((address_space(3))) void*)l, 16, 0, 0);
}

// ---------------- fp32 -> bf16 bulk cast ----------------
__global__ __launch_bounds__(256) void cast_kernel(const float* __restrict__ in,
                                                   u16* __restrict__ out, int n8) {
  int i = blockIdx.x * 256 + threadIdx.x;
  if (i >= n8) return;
  const float4* p = (const float4*)in + (size_t)i * 2;
  float4 a = p[0], b = p[1];
  u16x8 o;
  o[0] = f2bf(a.x); o[1] = f2bf(a.y); o[2] = f2bf(a.z); o[3] = f2bf(a.w);
  o[4] = f2bf(b.x); o[5] = f2bf(b.y); o[6] = f2bf(b.z); o[7] = f2bf(b.w);
  *((u16x8*)out + i) = o;
}

// ---------------- fp32 [K][N] -> bf16 [N][K] transpose-cast ----------------
__global__ __launch_bounds__(256) void cast_transpose_kernel(
    const float* __restrict__ in, u16* __restrict__ out, int K, int N) {
  __shared__ float tile[64][65];
  int n0 = blockIdx.x * 64, k0 = blockIdx.y * 64;
  int tx = threadIdx.x & 63, ty = threadIdx.x >> 6;
#pragma unroll
  for (int i = 0; i < 64; i += 4)
    tile[ty + i][tx] = in[(size_t)(k0 + ty + i) * N + n0 + tx];
  __syncthreads();
#pragma unroll
  for (int i = 0; i < 64; i += 4)
    out[(size_t)(n0 + ty + i) * K + k0 + tx] = f2bf(tile[tx][ty + i]);
}

// ---------------- RMSNorm (fp32 in, bf16 out) ----------------
__global__ __launch_bounds__(256) void rmsnorm_kernel(const float* __restrict__ x,
                                                      const float* __restrict__ w,
                                                      u16* __restrict__ out) {
  __shared__ float red[4];
  int row = blockIdx.x, t = threadIdx.x;
  const float4* xr = (const float4*)(x + (size_t)row * D_MODEL);
  float4 a = xr[t * 2], b = xr[t * 2 + 1];
  float ss = a.x * a.x + a.y * a.y + a.z * a.z + a.w * a.w +
             b.x * b.x + b.y * b.y + b.z * b.z + b.w * b.w;
#pragma unroll
  for (int m = 1; m < 64; m <<= 1) ss += __shfl_xor(ss, m, 64);
  if ((t & 63) == 0) red[t >> 6] = ss;
  __syncthreads();
  float tot = red[0] + red[1] + red[2] + red[3];
  float sc = rsqrtf(tot * (1.0f / D_MODEL) + 1e-6f);
  const float4* wr = (const float4*)w;
  float4 wa = wr[t * 2], wb = wr[t * 2 + 1];
  u16x8 o;
  o[0] = f2bf(a.x * sc * wa.x); o[1] = f2bf(a.y * sc * wa.y);
  o[2] = f2bf(a.z * sc * wa.z); o[3] = f2bf(a.w * sc * wa.w);
  o[4] = f2bf(b.x * sc * wb.x); o[5] = f2bf(b.y * sc * wb.y);
  o[6] = f2bf(b.z * sc * wb.z); o[7] = f2bf(b.w * sc * wb.w);
  *((u16x8*)(out + (size_t)row * D_MODEL) + t) = o;
}

// ---------------- bf16 MFMA GEMM (m97 structure): C = A(MxK) @ Bt(NxK)^T ----
// BK=64, 128x128 tile, global_load_lds w16 into linear LDS, XCD swizzle.
// EPI: 0 = bf16 out, 1 = f32 out + fp32 residual, 2 = silu -> bf16 out
template <int EPI>
__global__ __launch_bounds__(256) void gemm_kernel(const u16* __restrict__ A,
                                                   const u16* __restrict__ Bt,
                                                   void* __restrict__ Cv,
                                                   const float* __restrict__ res,
                                                   int N, int K) {
  __shared__ __align__(16) u16 As[128 * 64];
  __shared__ __align__(16) u16 Bs[128 * 64];
  const int tid = threadIdx.x, lane = tid & 63, wave = tid >> 6;
  const int wm = wave >> 1, wn = wave & 1;
  const int cols = N >> 7;
  const int cpx = gridDim.x >> 3;          // blocks per XCD (grids all %8==0)
  const int bid = blockIdx.x;
  const int swz = (bid & 7) * cpx + (bid >> 3);
  const int bm = (swz / cols) * 128, bn = (swz % cols) * 128;
  const int r16 = lane & 15, kg = lane >> 4;
  const int srow = tid >> 3, scol = (tid & 7) * 8;
  const u16* ga = A + (size_t)(bm + srow) * K + scol;
  const u16* gb = Bt + (size_t)(bn + srow) * K + scol;
  u16* la = As + tid * 8;  // byte offset tid*16: wave-uniform base + lane*16
  u16* lb = Bs + tid * 8;
  f32x4 acc[4][4] = {};
  for (int k0 = 0; k0 < K; k0 += 64) {
    __syncthreads();  // prev compute done before overwrite
#pragma unroll
    for (int ri = 0; ri < 4; ++ri) {
      gll16(ga + (size_t)(ri * 32) * K + k0, la + ri * 2048);
      gll16(gb + (size_t)(ri * 32) * K + k0, lb + ri * 2048);
    }
    __syncthreads();  // compiler drains vmcnt(0) before barrier
#pragma unroll
    for (int s = 0; s < 2; ++s) {
      u16x8 af[4], bfr[4];
#pragma unroll
      for (int m = 0; m < 4; ++m)
        af[m] = *(const u16x8*)(As + (wm * 64 + m * 16 + r16) * 64 + s * 32 + kg * 8);
#pragma unroll
      for (int n = 0; n < 4; ++n)
        bfr[n] = *(const u16x8*)(Bs + (wn * 64 + n * 16 + r16) * 64 + s * 32 + kg * 8);
#pragma unroll
      for (int m = 0; m < 4; ++m)
#pragma unroll
        for (int n = 0; n < 4; ++n) acc[m][n] = mfma16(af[m], bfr[n], acc[m][n]);
    }
  }
#pragma unroll
  for (int m = 0; m < 4; ++m) {
    int r0 = bm + wm * 64 + m * 16 + kg * 4;
#pragma unroll
    for (int n = 0; n < 4; ++n) {
      int cc = bn + wn * 64 + n * 16 + r16;
#pragma unroll
      for (int r = 0; r < 4; ++r) {
        size_t idx = (size_t)(r0 + r) * N + cc;
        float v = acc[m][n][r];
        if (EPI == 1) {
          ((float*)Cv)[idx] = res[idx] + v;
        } else if (EPI == 0) {
          ((u16*)Cv)[idx] = f2bf(v);
        } else {
          float s = v / (1.0f + __expf(-v));
          ((u16*)Cv)[idx] = f2bf(s);
        }
      }
    }
  }
}

// ---------------- MFMA flash attention (round-3, verified) ----------------
template <bool CAUSAL, bool SELF>
__global__ __launch_bounds__(256) void attn_mfma_kernel(
    const u16* __restrict__ qp, const u16* __restrict__ kp,
    const u16* __restrict__ vp, u16* __restrict__ outp) {
  __shared__ __align__(16) u16 KsL[32 * 136];     // [key][d], pad 136
  __shared__ __align__(16) u16 Vt[128 * 40];      // [d][key], pad 40
  __shared__ __align__(16) u16 PsL[4][16 * 40];   // per-wave [qrow][key], pad 40
  const int tid = threadIdx.x, lane = tid & 63, wave = tid >> 6;
  const int qt = blockIdx.x, b = blockIdx.y >> 4, h = blockIdx.y & 15;
  const int q0 = qt * 64;
  const int r16 = lane & 15, g4 = lane >> 4;

  const size_t qstr = SELF ? 6144 : 2048;
  const u16* qrow = qp + (size_t)(b * SEQ + q0 + wave * 16 + r16) * qstr + h * HD + g4 * 8;
  u16x8 aq[4];
#pragma unroll
  for (int ks = 0; ks < 4; ++ks) aq[ks] = *(const u16x8*)(qrow + ks * 32);

  f32x4 acc_o[8] = {};
  float m_run[4] = {-1e30f, -1e30f, -1e30f, -1e30f};
  float l_run[4] = {0.f, 0.f, 0.f, 0.f};
  const int wqmax = q0 + wave * 16 + 15;
  const int ntiles = CAUSAL ? (q0 + 64) / 32 : SEQ / 32;
  const float scale = 0.088388347648318447f;  // 1/sqrt(128)

  for (int kt = 0; kt < ntiles; ++kt) {
    __syncthreads();
#pragma unroll
    for (int it = 0; it < 2; ++it) {
      int ch = it * 256 + tid;
      int row = ch >> 4, col = (ch & 15) * 8;
      int key = kt * 32 + row;
      const u16 *ksrc, *vsrc;
      if (SELF) {
        const u16* base = kp + (size_t)(b * SEQ + key) * 6144 + h * HD + col;
        ksrc = base + 2048;
        vsrc = base + 4096;
      } else {
        size_t o = ((size_t)(b * SEQ + key) * 4 + (h >> 2)) * HD + col;
        ksrc = kp + o; vsrc = vp + o;
      }
      u16x8 kv = *(const u16x8*)ksrc;
      u16x8 vv = *(const u16x8*)vsrc;
      *(u16x8*)(KsL + row * 136 + col) = kv;
#pragma unroll
      for (int j = 0; j < 8; ++j) Vt[(col + j) * 40 + row] = vv[j];
    }
    __syncthreads();
    if (CAUSAL && kt * 32 > wqmax) continue;

    f32x4 s[2] = {};
#pragma unroll
    for (int nb = 0; nb < 2; ++nb)
#pragma unroll
      for (int ks = 0; ks < 4; ++ks) {
        u16x8 kf = *(const u16x8*)(KsL + (nb * 16 + r16) * 136 + ks * 32 + g4 * 8);
        s[nb] = mfma16(aq[ks], kf, s[nb]);
      }

    float p[2][4], corr[4];
#pragma unroll
    for (int rr = 0; rr < 4; ++rr) {
      float s0 = s[0][rr] * scale, s1 = s[1][rr] * scale;
      if (CAUSAL) {
        int qg = q0 + wave * 16 + g4 * 4 + rr;
        if (kt * 32 + r16 > qg) s0 = -1e30f;
        if (kt * 32 + 16 + r16 > qg) s1 = -1e30f;
      }
      float pm = fmaxf(s0, s1);
      pm = fmaxf(pm, __shfl_xor(pm, 1, 64));
      pm = fmaxf(pm, __shfl_xor(pm, 2, 64));
      pm = fmaxf(pm, __shfl_xor(pm, 4, 64));
      pm = fmaxf(pm, __shfl_xor(pm, 8, 64));
      float mn = fmaxf(m_run[rr], pm);
      corr[rr] = __expf(m_run[rr] - mn);
      m_run[rr] = mn;
      float p0 = __expf(s0 - mn), p1 = __expf(s1 - mn);
      p[0][rr] = p0; p[1][rr] = p1;
      float ps = p0 + p1;
      ps += __shfl_xor(ps, 1, 64);
      ps += __shfl_xor(ps, 2, 64);
      ps += __shfl_xor(ps, 4, 64);
      ps += __shfl_xor(ps, 8, 64);
      l_run[rr] = l_run[rr] * corr[rr] + ps;
    }

    u16* pw = PsL[wave];
#pragma unroll
    for (int rr = 0; rr < 4; ++rr) {
      int rowo = (g4 * 4 + rr) * 40;
      pw[rowo + r16] = f2bf(p[0][rr]);
      pw[rowo + 16 + r16] = f2bf(p[1][rr]);
    }
#pragma unroll
    for (int s8 = 0; s8 < 8; ++s8)
#pragma unroll
      for (int rr = 0; rr < 4; ++rr) acc_o[s8][rr] *= corr[rr];

    u16x8 pa = *(const u16x8*)(pw + r16 * 40 + g4 * 8);

#pragma unroll
    for (int s8 = 0; s8 < 8; ++s8) {
      u16x8 vb = *(const u16x8*)(Vt + (s8 * 16 + r16) * 40 + g4 * 8);
      acc_o[s8] = mfma16(pa, vb, acc_o[s8]);
    }
  }

  u16* ob = outp + (size_t)(b * SEQ + q0 + wave * 16 + g4 * 4) * D_MODEL + h * HD + r16;
#pragma unroll
  for (int rr = 0; rr < 4; ++rr) {
    float inv = 1.0f / l_run[rr];
#pragma unroll
    for (int s8 = 0; s8 < 8; ++s8)
      ob[(size_t)rr * D_MODEL + s8 * 16] = f2bf(acc_o[s8][rr] * inv);
  }
}

extern "C" void kernel_launch(void* const* d_in, const int* in_sizes, int n_in,
                              void* d_out, int out_size, void* d_ws, size_t ws_size,
                              hipStream_t stream) {
  const float* x          = (const float*)d_in[0];
  const float* k_ctx      = (const float*)d_in[1];
  const float* v_ctx      = (const float*)d_in[2];
  const float* wq         = (const float*)d_in[3];
  const float* wo_cross   = (const float*)d_in[4];
  const float* norm_q_w   = (const float*)d_in[5];
  const float* wqkv       = (const float*)d_in[6];
  const float* wo_self    = (const float*)d_in[7];
  const float* norm_qkv_w = (const float*)d_in[8];
  const float* ffn_w1     = (const float*)d_in[9];
  const float* ffn_w2     = (const float*)d_in[10];
  const float* ffn_norm_w = (const float*)d_in[11];
  float* out = (float*)d_out;

  char* ws = (char*)d_ws;
  size_t off = 0;
  auto alloc_u16 = [&](size_t n) { u16* p = (u16*)(ws + off); off += n * 2; return p; };
  auto alloc_f32 = [&](size_t n) { float* p = (float*)(ws + off); off += n * 4; return p; };
  u16* wq_bf   = alloc_u16((size_t)2048 * 2048);   // [N][K] transposed
  u16* woc_bf  = alloc_u16((size_t)2048 * 2048);
  u16* wqkv_bf = alloc_u16((size_t)2048 * 6144);
  u16* wos_bf  = alloc_u16((size_t)2048 * 2048);
  u16* w1_bf   = alloc_u16((size_t)2048 * 8192);
  u16* w2_bf   = alloc_u16((size_t)8192 * 2048);
  u16* xn_bf   = alloc_u16((size_t)ROWS * 2048);
  u16* qkv_bf  = alloc_u16((size_t)ROWS * 6144);
  u16* attn_bf = alloc_u16((size_t)ROWS * 2048);
  float* x1    = alloc_f32((size_t)ROWS * 2048);
  float* x2    = alloc_f32((size_t)ROWS * 2048);
  u16* q_bf  = qkv_bf;
  u16* h1_bf = qkv_bf;                 // qkv + attn regions hold FFN hidden
  u16* kc_bf = (u16*)x2;               // x2 unused until self-attn output GEMM
  u16* vc_bf = kc_bf + (size_t)BATCH * SEQ * 4 * HD;

  auto castT = [&](const float* src, u16* dst, int K, int N) {
    cast_transpose_kernel<<<dim3(N / 64, K / 64), 256, 0, stream>>>(src, dst, K, N);
  };
  castT(wq, wq_bf, 2048, 2048);
  castT(wo_cross, woc_bf, 2048, 2048);
  castT(wqkv, wqkv_bf, 2048, 6144);
  castT(wo_self, wos_bf, 2048, 2048);
  castT(ffn_w1, w1_bf, 2048, 8192);
  castT(ffn_w2, w2_bf, 8192, 2048);
  {
    int n8 = (int)((size_t)BATCH * SEQ * 4 * HD / 8);
    cast_kernel<<<dim3((n8 + 255) / 256), dim3(256), 0, stream>>>(k_ctx, kc_bf, n8);
    cast_kernel<<<dim3((n8 + 255) / 256), dim3(256), 0, stream>>>(v_ctx, vc_bf, n8);
  }

  // ---- cross attention (GQA) ----
  rmsnorm_kernel<<<ROWS, 256, 0, stream>>>(x, norm_q_w, xn_bf);
  gemm_kernel<0><<<dim3((ROWS / 128) * (2048 / 128)), 256, 0, stream>>>(
      xn_bf, wq_bf, q_bf, nullptr, 2048, 2048);
  attn_mfma_kernel<false, false><<<dim3(SEQ / 64, BATCH * NH), 256, 0, stream>>>(
      q_bf, kc_bf, vc_bf, attn_bf);
  gemm_kernel<1><<<dim3((ROWS / 128) * (2048 / 128)), 256, 0, stream>>>(
      attn_bf, woc_bf, x1, x, 2048, 2048);

  // ---- causal self attention ----
  rmsnorm_kernel<<<ROWS, 256, 0, stream>>>(x1, norm_qkv_w, xn_bf);
  gemm_kernel<0><<<dim3((ROWS / 128) * (6144 / 128)), 256, 0, stream>>>(
      xn_bf, wqkv_bf, qkv_bf, nullptr, 6144, 2048);
  attn_mfma_kernel<true, true><<<dim3(SEQ / 64, BATCH * NH), 256, 0, stream>>>(
      qkv_bf, qkv_bf, qkv_bf, attn_bf);
  gemm_kernel<1><<<dim3((ROWS / 128) * (2048 / 128)), 256, 0, stream>>>(
      attn_bf, wos_bf, x2, x1, 2048, 2048);

  // ---- FFN (SiLU) ----
  rmsnorm_kernel<<<ROWS, 256, 0, stream>>>(x2, ffn_norm_w, xn_bf);
  gemm_kernel<2><<<dim3((ROWS / 128) * (8192 / 128)), 256, 0, stream>>>(
      xn_bf, w1_bf, h1_bf, nullptr, 8192, 2048);
  gemm_kernel<1><<<dim3((ROWS / 128) * (2048 / 128)), 256, 0, stream>>>(
      h1_bf, w2_bf, out, x2, 2048, 8192);
}

// Round 5
// 1079.179 us; speedup vs baseline: 6.0105x; 1.6261x over previous
//
#include <hip/hip_runtime.h>
#include <math.h>

typedef unsigned short u16;
typedef __attribute__((ext_vector_type(4))) u16 u16x4;
typedef __attribute__((ext_vector_type(8))) u16 u16x8;
typedef __attribute__((ext_vector_type(8))) __bf16 bf16x8;
typedef __attribute__((ext_vector_type(4))) float f32x4;
typedef __attribute__((ext_vector_type(16))) float f32x16;
typedef __attribute__((ext_vector_type(4))) unsigned u32x4;

#define D_MODEL 2048
#define SEQ 2048
#define BATCH 2
#define NH 16
#define HD 128
#define DFF 8192
#define ROWS (BATCH * SEQ)  // 4096

__device__ __forceinline__ u16 f2bf(float f) {
  union { float f; unsigned u; } v; v.f = f;
  unsigned r = v.u + 0x7FFFu + ((v.u >> 16) & 1u);
  return (u16)(r >> 16);
}
__device__ __forceinline__ u16 to_bf16(float f) { return f2bf(f); }
__device__ __forceinline__ u16 to_bf16(u16 v) { return v; }

__device__ __forceinline__ f32x4 mfma16(u16x8 a, u16x8 b, f32x4 c) {
  return __builtin_amdgcn_mfma_f32_16x16x32_bf16(
      __builtin_bit_cast(bf16x8, a), __builtin_bit_cast(bf16x8, b), c, 0, 0, 0);
}
__device__ __forceinline__ f32x16 mfma32(u16x8 a, u16x8 b, f32x16 c) {
  return __builtin_amdgcn_mfma_f32_32x32x16_bf16(
      __builtin_bit_cast(bf16x8, a), __builtin_bit_cast(bf16x8, b), c, 0, 0, 0);
}

__device__ __forceinline__ void gll16(const void* g, void* l) {
  __builtin_amdgcn_global_load_lds(
      (const __attribute__((address_space(1))) void*)g,
      (__attribute__((address_space(3))) void*)l, 16, 0, 0);
}

// ---------------- fp32 -> bf16 bulk cast ----------------
__global__ __launch_bounds__(256) void cast_kernel(const float* __restrict__ in,
                                                   u16* __restrict__ out, int n8) {
  int i = blockIdx.x * 256 + threadIdx.x;
  if (i >= n8) return;
  const float4* p = (const float4*)in + (size_t)i * 2;
  float4 a = p[0], b = p[1];
  u16x8 o;
  o[0] = f2bf(a.x); o[1] = f2bf(a.y); o[2] = f2bf(a.z); o[3] = f2bf(a.w);
  o[4] = f2bf(b.x); o[5] = f2bf(b.y); o[6] = f2bf(b.z); o[7] = f2bf(b.w);
  *((u16x8*)out + i) = o;
}

// ---------------- fp32 [K][N] -> bf16 [N][K] transpose-cast (weights) -------
__global__ __launch_bounds__(256) void cast_transpose_kernel(
    const float* __restrict__ in, u16* __restrict__ out, int K, int N) {
  __shared__ float tile[64][65];
  int n0 = blockIdx.x * 64, k0 = blockIdx.y * 64;
  int tx = threadIdx.x & 63, ty = threadIdx.x >> 6;
#pragma unroll
  for (int i = 0; i < 64; i += 4)
    tile[ty + i][tx] = in[(size_t)(k0 + ty + i) * N + n0 + tx];
  __syncthreads();
#pragma unroll
  for (int i = 0; i < 64; i += 4)
    out[(size_t)(n0 + ty + i) * K + k0 + tx] = f2bf(tile[tx][ty + i]);
}

// ---------------- build V^T: per (b,zh): [SEQ][128] -> [128][SEQ] bf16 ------
template <typename ST>
__global__ __launch_bounds__(256) void build_vt_kernel(
    const ST* __restrict__ src, u16* __restrict__ dst, int HZ,
    size_t src_b_stride, size_t src_h_stride, int src_tok_stride) {
  __shared__ u16 tl[64][72];
  int z = blockIdx.z, zb = z / HZ, zh = z % HZ;
  const ST* s = src + (size_t)zb * src_b_stride + (size_t)zh * src_h_stride;
  int t0 = blockIdx.x * 64, d0 = blockIdx.y * 64;
  int rr = threadIdx.x >> 4, cc = (threadIdx.x & 15) * 4;
#pragma unroll
  for (int pp = 0; pp < 4; ++pp) {
    int t = pp * 16 + rr;
    const ST* sp = s + (size_t)(t0 + t) * src_tok_stride + d0 + cc;
#pragma unroll
    for (int j = 0; j < 4; ++j) tl[t][cc + j] = to_bf16(sp[j]);
  }
  __syncthreads();
  u16* dp = dst + (size_t)z * HD * SEQ;
#pragma unroll
  for (int pp = 0; pp < 4; ++pp) {
    int d = pp * 16 + rr;
    u16x4 w;
#pragma unroll
    for (int j = 0; j < 4; ++j) w[j] = tl[cc + j][d];
    *(u16x4*)(dp + (size_t)(d0 + d) * SEQ + t0 + cc) = w;
  }
}

// ---------------- RMSNorm (fp32 in, bf16 out) ----------------
__global__ __launch_bounds__(256) void rmsnorm_kernel(const float* __restrict__ x,
                                                      const float* __restrict__ w,
                                                      u16* __restrict__ out) {
  __shared__ float red[4];
  int row = blockIdx.x, t = threadIdx.x;
  const float4* xr = (const float4*)(x + (size_t)row * D_MODEL);
  float4 a = xr[t * 2], b = xr[t * 2 + 1];
  float ss = a.x * a.x + a.y * a.y + a.z * a.z + a.w * a.w +
             b.x * b.x + b.y * b.y + b.z * b.z + b.w * b.w;
#pragma unroll
  for (int m = 1; m < 64; m <<= 1) ss += __shfl_xor(ss, m, 64);
  if ((t & 63) == 0) red[t >> 6] = ss;
  __syncthreads();
  float tot = red[0] + red[1] + red[2] + red[3];
  float sc = rsqrtf(tot * (1.0f / D_MODEL) + 1e-6f);
  const float4* wr = (const float4*)w;
  float4 wa = wr[t * 2], wb = wr[t * 2 + 1];
  u16x8 o;
  o[0] = f2bf(a.x * sc * wa.x); o[1] = f2bf(a.y * sc * wa.y);
  o[2] = f2bf(a.z * sc * wa.z); o[3] = f2bf(a.w * sc * wa.w);
  o[4] = f2bf(b.x * sc * wb.x); o[5] = f2bf(b.y * sc * wb.y);
  o[6] = f2bf(b.z * sc * wb.z); o[7] = f2bf(b.w * sc * wb.w);
  *((u16x8*)(out + (size_t)row * D_MODEL) + t) = o;
}

// ---------------- bf16 MFMA GEMM (m97 structure): C = A(MxK) @ Bt(NxK)^T ----
template <int EPI>
__global__ __launch_bounds__(256) void gemm_kernel(const u16* __restrict__ A,
                                                   const u16* __restrict__ Bt,
                                                   void* __restrict__ Cv,
                                                   const float* __restrict__ res,
                                                   int N, int K) {
  __shared__ __align__(16) u16 As[128 * 64];
  __shared__ __align__(16) u16 Bs[128 * 64];
  const int tid = threadIdx.x, lane = tid & 63, wave = tid >> 6;
  const int wm = wave >> 1, wn = wave & 1;
  const int cols = N >> 7;
  const int cpx = gridDim.x >> 3;
  const int bid = blockIdx.x;
  const int swz = (bid & 7) * cpx + (bid >> 3);
  const int bm = (swz / cols) * 128, bn = (swz % cols) * 128;
  const int r16 = lane & 15, kg = lane >> 4;
  const int srow = tid >> 3, scol = (tid & 7) * 8;
  const u16* ga = A + (size_t)(bm + srow) * K + scol;
  const u16* gb = Bt + (size_t)(bn + srow) * K + scol;
  u16* la = As + tid * 8;
  u16* lb = Bs + tid * 8;
  f32x4 acc[4][4] = {};
  for (int k0 = 0; k0 < K; k0 += 64) {
    __syncthreads();
#pragma unroll
    for (int ri = 0; ri < 4; ++ri) {
      gll16(ga + (size_t)(ri * 32) * K + k0, la + ri * 2048);
      gll16(gb + (size_t)(ri * 32) * K + k0, lb + ri * 2048);
    }
    __syncthreads();
#pragma unroll
    for (int s = 0; s < 2; ++s) {
      u16x8 af[4], bfr[4];
#pragma unroll
      for (int m = 0; m < 4; ++m)
        af[m] = *(const u16x8*)(As + (wm * 64 + m * 16 + r16) * 64 + s * 32 + kg * 8);
#pragma unroll
      for (int n = 0; n < 4; ++n)
        bfr[n] = *(const u16x8*)(Bs + (wn * 64 + n * 16 + r16) * 64 + s * 32 + kg * 8);
#pragma unroll
      for (int m = 0; m < 4; ++m)
#pragma unroll
        for (int n = 0; n < 4; ++n) acc[m][n] = mfma16(af[m], bfr[n], acc[m][n]);
    }
  }
#pragma unroll
  for (int m = 0; m < 4; ++m) {
    int r0 = bm + wm * 64 + m * 16 + kg * 4;
#pragma unroll
    for (int n = 0; n < 4; ++n) {
      int cc = bn + wn * 64 + n * 16 + r16;
#pragma unroll
      for (int r = 0; r < 4; ++r) {
        size_t idx = (size_t)(r0 + r) * N + cc;
        float v = acc[m][n][r];
        if (EPI == 1) {
          ((float*)Cv)[idx] = res[idx] + v;
        } else if (EPI == 0) {
          ((u16*)Cv)[idx] = f2bf(v);
        } else {
          float s = v / (1.0f + __expf(-v));
          ((u16*)Cv)[idx] = f2bf(s);
        }
      }
    }
  }
}

// ---------------- flash attention v2: 8 warps x 32 q, KVBLK=64, 32x32 MFMA --
// Swapped operands: S^T = mfma(K,Q); softmax in-register (q = lane&31 column);
// P -> B-frag via v_cvt_pk_bf16_f32 + v_permlane32_swap_b32.
// K staged [64][128] u16 with 16B-chunk slot s = dc ^ (key&15) (involution).
// V^T staged [128][64] u16 with slot s = kc ^ (d&7). Both via global_load_lds.
template <bool CAUSAL, bool SELF>
__global__ __launch_bounds__(512, 2) void attn2_kernel(
    const u16* __restrict__ qp, const u16* __restrict__ kp,
    const u16* __restrict__ vtp, u16* __restrict__ outp) {
  __shared__ __align__(16) u16 Kl[64 * 128];   // 16 KB
  __shared__ __align__(16) u16 Vl[128 * 64];   // 16 KB
  const int tid = threadIdx.x, lane = tid & 63, wave = tid >> 6;
  const int lo = lane & 31, hi = lane >> 5;
  const int qt = blockIdx.x, bh = blockIdx.y, b = bh >> 4, h = bh & 15;
  const int qw0 = qt * 256 + wave * 32;
  const int qg = qw0 + lo;
  const size_t qstr = SELF ? 6144 : 2048;
  const size_t kstr = SELF ? 6144 : 512;
  const u16* qbase = qp + ((size_t)b * SEQ + qg) * qstr + h * HD;
  const u16* kbase = kp + (size_t)b * SEQ * kstr + (SELF ? (2048 + h * HD) : ((h >> 2) * HD));
  const u16* vbase = vtp + (size_t)(SELF ? (b * NH + h) : (b * 4 + (h >> 2))) * HD * SEQ;

  u16x8 qf[8];  // B-frag: Q[q=lo][dc*16 + hi*8 + j]
#pragma unroll
  for (int dc = 0; dc < 8; ++dc) qf[dc] = *(const u16x8*)(qbase + dc * 16 + hi * 8);

  f32x16 o[4] = {};  // O^T[d = mb*32 + (r&3)+8*(r>>2)+4*hi][q=lo]
  float m_run = -3e38f, l_run = 0.f;
  const int ntiles = CAUSAL ? qt * 4 + 4 : SEQ / 64;
  const float scale = 0.088388347648318447f;  // 1/sqrt(128)

  for (int kt = 0; kt < ntiles; ++kt) {
    __syncthreads();
#pragma unroll
    for (int i = 0; i < 2; ++i) {
      int c = i * 512 + tid;
      int krow = c >> 4, ks = c & 15;
      gll16(kbase + (size_t)(kt * 64 + krow) * kstr + ((ks ^ (krow & 15)) * 8),
            Kl + (size_t)c * 8);
      int vd = c >> 3, vs = c & 7;
      gll16(vbase + (size_t)vd * SEQ + kt * 64 + ((vs ^ (vd & 7)) * 8),
            Vl + (size_t)c * 8);
    }
    __syncthreads();
    if (CAUSAL && kt * 64 > qw0 + 31) continue;

    // ---- QK^T (S^T), 16 mfma ----
    f32x16 s01[2] = {};
#pragma unroll
    for (int k2 = 0; k2 < 2; ++k2) {
      int key = k2 * 32 + lo;
#pragma unroll
      for (int mf = 0; mf < 8; ++mf) {
        int dc = mf * 2 + hi;
        u16x8 kf = *(const u16x8*)(Kl + key * 128 + ((dc ^ (key & 15)) * 8));
        s01[k2] = mfma32(kf, qf[mf], s01[k2]);
      }
    }

    // ---- softmax over 64 keys, in-register ----
    float sv[32];
    float pm = -3e38f;
#pragma unroll
    for (int k2 = 0; k2 < 2; ++k2)
#pragma unroll
      for (int r = 0; r < 16; ++r) {
        float v = s01[k2][r];
        if (CAUSAL) {
          int key = kt * 64 + k2 * 32 + (r & 3) + 8 * (r >> 2) + 4 * hi;
          if (key > qg) v = -3e38f;
        }
        sv[k2 * 16 + r] = v;
        pm = fmaxf(pm, v);
      }
    pm = fmaxf(pm, __shfl_xor(pm, 32, 64));
    float mn = fmaxf(m_run, pm);
    float corr = __expf((m_run - mn) * scale);
    m_run = mn;

    float ps = 0.f;
    u16x8 pf[4];
#pragma unroll
    for (int k2 = 0; k2 < 2; ++k2)
#pragma unroll
      for (int hf = 0; hf < 2; ++hf) {
        float p8[8];
#pragma unroll
        for (int j = 0; j < 8; ++j) {
          p8[j] = __expf((sv[k2 * 16 + hf * 8 + j] - mn) * scale);
          ps += p8[j];
        }
        unsigned w0, w1, w2, w3;
        asm("v_cvt_pk_bf16_f32 %0, %1, %2" : "=v"(w0) : "v"(p8[0]), "v"(p8[1]));
        asm("v_cvt_pk_bf16_f32 %0, %1, %2" : "=v"(w1) : "v"(p8[2]), "v"(p8[3]));
        asm("v_cvt_pk_bf16_f32 %0, %1, %2" : "=v"(w2) : "v"(p8[4]), "v"(p8[5]));
        asm("v_cvt_pk_bf16_f32 %0, %1, %2" : "=v"(w3) : "v"(p8[6]), "v"(p8[7]));
        asm("v_permlane32_swap_b32 %0, %1" : "+v"(w0), "+v"(w2));
        asm("v_permlane32_swap_b32 %0, %1" : "+v"(w1), "+v"(w3));
        u32x4 fr; fr[0] = w0; fr[1] = w1; fr[2] = w2; fr[3] = w3;
        pf[k2 * 2 + hf] = __builtin_bit_cast(u16x8, fr);
      }
    ps += __shfl_xor(ps, 32, 64);
    l_run = l_run * corr + ps;

#pragma unroll
    for (int mb = 0; mb < 4; ++mb)
#pragma unroll
      for (int r = 0; r < 16; ++r) o[mb][r] *= corr;

    // ---- PV (O^T += V^T P^T), 16 mfma ----
#pragma unroll
    for (int kc = 0; kc < 4; ++kc) {
      int vcs = kc * 2 + hi;
#pragma unroll
      for (int mb = 0; mb < 4; ++mb) {
        int d = mb * 32 + lo;
        u16x8 vf = *(const u16x8*)(Vl + d * 64 + ((vcs ^ (d & 7)) * 8));
        o[mb] = mfma32(vf, pf[kc], o[mb]);
      }
    }
  }

  // ---- epilogue ----
  float inv = 1.0f / l_run;
  u16* ob = outp + ((size_t)b * SEQ + qg) * D_MODEL + h * HD + 4 * hi;
#pragma unroll
  for (int mb = 0; mb < 4; ++mb)
#pragma unroll
    for (int rq = 0; rq < 4; ++rq) {
      u16x4 w;
#pragma unroll
      for (int j = 0; j < 4; ++j) w[j] = f2bf(o[mb][rq * 4 + j] * inv);
      *(u16x4*)(ob + mb * 32 + rq * 8) = w;
    }
}

extern "C" void kernel_launch(void* const* d_in, const int* in_sizes, int n_in,
                              void* d_out, int out_size, void* d_ws, size_t ws_size,
                              hipStream_t stream) {
  const float* x          = (const float*)d_in[0];
  const float* k_ctx      = (const float*)d_in[1];
  const float* v_ctx      = (const float*)d_in[2];
  const float* wq         = (const float*)d_in[3];
  const float* wo_cross   = (const float*)d_in[4];
  const float* norm_q_w   = (const float*)d_in[5];
  const float* wqkv       = (const float*)d_in[6];
  const float* wo_self    = (const float*)d_in[7];
  const float* norm_qkv_w = (const float*)d_in[8];
  const float* ffn_w1     = (const float*)d_in[9];
  const float* ffn_w2     = (const float*)d_in[10];
  const float* ffn_norm_w = (const float*)d_in[11];
  float* out = (float*)d_out;

  char* ws = (char*)d_ws;
  size_t off = 0;
  auto alloc_u16 = [&](size_t n) { u16* p = (u16*)(ws + off); off += n * 2; return p; };
  auto alloc_f32 = [&](size_t n) { float* p = (float*)(ws + off); off += n * 4; return p; };
  u16* wq_bf   = alloc_u16((size_t)2048 * 2048);   // [N][K]
  u16* woc_bf  = alloc_u16((size_t)2048 * 2048);
  u16* wqkv_bf = alloc_u16((size_t)2048 * 6144);
  u16* wos_bf  = alloc_u16((size_t)2048 * 2048);
  u16* w1_bf   = alloc_u16((size_t)2048 * 8192);
  u16* w2_bf   = alloc_u16((size_t)8192 * 2048);
  u16* xn_bf   = alloc_u16((size_t)ROWS * 2048);
  u16* qkv_bf  = alloc_u16((size_t)ROWS * 6144);
  u16* attn_bf = alloc_u16((size_t)ROWS * 2048);
  float* x1    = alloc_f32((size_t)ROWS * 2048);
  float* x2    = alloc_f32((size_t)ROWS * 2048);
  u16* q_bf    = qkv_bf;
  u16* h1_bf   = qkv_bf;                // qkv + attn regions hold FFN hidden
  u16* kc_bf   = (u16*)x2;              // x2 dead until self-attn out-GEMM
  u16* vt_ctx  = kc_bf + (size_t)BATCH * SEQ * 4 * HD;   // [b][g][128][SEQ]
  u16* vt_self = xn_bf;                 // xn dead between qkv-GEMM and FFN norm

  auto castT = [&](const float* src, u16* dst, int K, int N) {
    cast_transpose_kernel<<<dim3(N / 64, K / 64), 256, 0, stream>>>(src, dst, K, N);
  };
  castT(wq, wq_bf, 2048, 2048);
  castT(wo_cross, woc_bf, 2048, 2048);
  castT(wqkv, wqkv_bf, 2048, 6144);
  castT(wo_self, wos_bf, 2048, 2048);
  castT(ffn_w1, w1_bf, 2048, 8192);
  castT(ffn_w2, w2_bf, 8192, 2048);
  {
    int n8 = (int)((size_t)BATCH * SEQ * 4 * HD / 8);
    cast_kernel<<<dim3((n8 + 255) / 256), dim3(256), 0, stream>>>(k_ctx, kc_bf, n8);
  }
  // V^T for cross-attn: f32 (B,T,4,128) -> bf16 [b*4+g][128][SEQ]
  build_vt_kernel<float><<<dim3(SEQ / 64, HD / 64, BATCH * 4), 256, 0, stream>>>(
      v_ctx, vt_ctx, 4, (size_t)SEQ * 512, (size_t)HD, 512);

  // ---- cross attention (GQA) ----
  rmsnorm_kernel<<<ROWS, 256, 0, stream>>>(x, norm_q_w, xn_bf);
  gemm_kernel<0><<<dim3((ROWS / 128) * (2048 / 128)), 256, 0, stream>>>(
      xn_bf, wq_bf, q_bf, nullptr, 2048, 2048);
  attn2_kernel<false, false><<<dim3(SEQ / 256, BATCH * NH), 512, 0, stream>>>(
      q_bf, kc_bf, vt_ctx, attn_bf);
  gemm_kernel<1><<<dim3((ROWS / 128) * (2048 / 128)), 256, 0, stream>>>(
      attn_bf, woc_bf, x1, x, 2048, 2048);

  // ---- causal self attention ----
  rmsnorm_kernel<<<ROWS, 256, 0, stream>>>(x1, norm_qkv_w, xn_bf);
  gemm_kernel<0><<<dim3((ROWS / 128) * (6144 / 128)), 256, 0, stream>>>(
      xn_bf, wqkv_bf, qkv_bf, nullptr, 6144, 2048);
  // V^T for self-attn: bf16 v-part of qkv (stride 6144) -> [b*16+h][128][SEQ]
  build_vt_kernel<u16><<<dim3(SEQ / 64, HD / 64, BATCH * NH), 256, 0, stream>>>(
      qkv_bf + 4096, vt_self, NH, (size_t)SEQ * 6144, (size_t)HD, 6144);
  attn2_kernel<true, true><<<dim3(SEQ / 256, BATCH * NH), 512, 0, stream>>>(
      qkv_bf, qkv_bf, vt_self, attn_bf);
  gemm_kernel<1><<<dim3((ROWS / 128) * (2048 / 128)), 256, 0, stream>>>(
      attn_bf, wos_bf, x2, x1, 2048, 2048);

  // ---- FFN (SiLU) ----
  rmsnorm_kernel<<<ROWS, 256, 0, stream>>>(x2, ffn_norm_w, xn_bf);
  gemm_kernel<2><<<dim3((ROWS / 128) * (8192 / 128)), 256, 0, stream>>>(
      xn_bf, w1_bf, h1_bf, nullptr, 8192, 2048);
  gemm_kernel<1><<<dim3((ROWS / 128) * (2048 / 128)), 256, 0, stream>>>(
      h1_bf, w2_bf, out, x2, 2048, 8192);
}

// Round 6
// 951.150 us; speedup vs baseline: 6.8196x; 1.1346x over previous
//
#include <hip/hip_runtime.h>
#include <math.h>

typedef unsigned short u16;
typedef __attribute__((ext_vector_type(4))) u16 u16x4;
typedef __attribute__((ext_vector_type(8))) u16 u16x8;
typedef __attribute__((ext_vector_type(8))) __bf16 bf16x8;
typedef __attribute__((ext_vector_type(4))) float f32x4;
typedef __attribute__((ext_vector_type(16))) float f32x16;
typedef __attribute__((ext_vector_type(4))) unsigned u32x4;

#define D_MODEL 2048
#define SEQ 2048
#define BATCH 2
#define NH 16
#define HD 128
#define DFF 8192
#define ROWS (BATCH * SEQ)  // 4096

__device__ __forceinline__ u16 f2bf(float f) {
  union { float f; unsigned u; } v; v.f = f;
  unsigned r = v.u + 0x7FFFu + ((v.u >> 16) & 1u);
  return (u16)(r >> 16);
}
__device__ __forceinline__ u16 to_bf16(float f) { return f2bf(f); }
__device__ __forceinline__ u16 to_bf16(u16 v) { return v; }

__device__ __forceinline__ f32x4 mfma16(u16x8 a, u16x8 b, f32x4 c) {
  return __builtin_amdgcn_mfma_f32_16x16x32_bf16(
      __builtin_bit_cast(bf16x8, a), __builtin_bit_cast(bf16x8, b), c, 0, 0, 0);
}
__device__ __forceinline__ f32x16 mfma32(u16x8 a, u16x8 b, f32x16 c) {
  return __builtin_amdgcn_mfma_f32_32x32x16_bf16(
      __builtin_bit_cast(bf16x8, a), __builtin_bit_cast(bf16x8, b), c, 0, 0, 0);
}

__device__ __forceinline__ void gll16(const void* g, void* l) {
  __builtin_amdgcn_global_load_lds(
      (const __attribute__((address_space(1))) void*)g,
      (__attribute__((address_space(3))) void*)l, 16, 0, 0);
}

// ---------------- fp32 -> bf16 bulk cast ----------------
__global__ __launch_bounds__(256) void cast_kernel(const float* __restrict__ in,
                                                   u16* __restrict__ out, int n8) {
  int i = blockIdx.x * 256 + threadIdx.x;
  if (i >= n8) return;
  const float4* p = (const float4*)in + (size_t)i * 2;
  float4 a = p[0], b = p[1];
  u16x8 o;
  o[0] = f2bf(a.x); o[1] = f2bf(a.y); o[2] = f2bf(a.z); o[3] = f2bf(a.w);
  o[4] = f2bf(b.x); o[5] = f2bf(b.y); o[6] = f2bf(b.z); o[7] = f2bf(b.w);
  *((u16x8*)out + i) = o;
}

// ---------------- fp32 [K][N] -> bf16 [N][K] transpose-cast (weights) -------
__global__ __launch_bounds__(256) void cast_transpose_kernel(
    const float* __restrict__ in, u16* __restrict__ out, int K, int N) {
  __shared__ float tile[64][65];
  int n0 = blockIdx.x * 64, k0 = blockIdx.y * 64;
  int tx = threadIdx.x & 63, ty = threadIdx.x >> 6;
#pragma unroll
  for (int i = 0; i < 64; i += 4)
    tile[ty + i][tx] = in[(size_t)(k0 + ty + i) * N + n0 + tx];
  __syncthreads();
#pragma unroll
  for (int i = 0; i < 64; i += 4)
    out[(size_t)(n0 + ty + i) * K + k0 + tx] = f2bf(tile[tx][ty + i]);
}

// ---------------- build V^T: per (b,zh): [SEQ][128] -> [128][SEQ] bf16 ------
template <typename ST>
__global__ __launch_bounds__(256) void build_vt_kernel(
    const ST* __restrict__ src, u16* __restrict__ dst, int HZ,
    size_t src_b_stride, size_t src_h_stride, int src_tok_stride) {
  __shared__ u16 tl[64][72];
  int z = blockIdx.z, zb = z / HZ, zh = z % HZ;
  const ST* s = src + (size_t)zb * src_b_stride + (size_t)zh * src_h_stride;
  int t0 = blockIdx.x * 64, d0 = blockIdx.y * 64;
  int rr = threadIdx.x >> 4, cc = (threadIdx.x & 15) * 4;
#pragma unroll
  for (int pp = 0; pp < 4; ++pp) {
    int t = pp * 16 + rr;
    const ST* sp = s + (size_t)(t0 + t) * src_tok_stride + d0 + cc;
#pragma unroll
    for (int j = 0; j < 4; ++j) tl[t][cc + j] = to_bf16(sp[j]);
  }
  __syncthreads();
  u16* dp = dst + (size_t)z * HD * SEQ;
#pragma unroll
  for (int pp = 0; pp < 4; ++pp) {
    int d = pp * 16 + rr;
    u16x4 w;
#pragma unroll
    for (int j = 0; j < 4; ++j) w[j] = tl[cc + j][d];
    *(u16x4*)(dp + (size_t)(d0 + d) * SEQ + t0 + cc) = w;
  }
}

// ---------------- RMSNorm (fp32 in, bf16 out) ----------------
__global__ __launch_bounds__(256) void rmsnorm_kernel(const float* __restrict__ x,
                                                      const float* __restrict__ w,
                                                      u16* __restrict__ out) {
  __shared__ float red[4];
  int row = blockIdx.x, t = threadIdx.x;
  const float4* xr = (const float4*)(x + (size_t)row * D_MODEL);
  float4 a = xr[t * 2], b = xr[t * 2 + 1];
  float ss = a.x * a.x + a.y * a.y + a.z * a.z + a.w * a.w +
             b.x * b.x + b.y * b.y + b.z * b.z + b.w * b.w;
#pragma unroll
  for (int m = 1; m < 64; m <<= 1) ss += __shfl_xor(ss, m, 64);
  if ((t & 63) == 0) red[t >> 6] = ss;
  __syncthreads();
  float tot = red[0] + red[1] + red[2] + red[3];
  float sc = rsqrtf(tot * (1.0f / D_MODEL) + 1e-6f);
  const float4* wr = (const float4*)w;
  float4 wa = wr[t * 2], wb = wr[t * 2 + 1];
  u16x8 o;
  o[0] = f2bf(a.x * sc * wa.x); o[1] = f2bf(a.y * sc * wa.y);
  o[2] = f2bf(a.z * sc * wa.z); o[3] = f2bf(a.w * sc * wa.w);
  o[4] = f2bf(b.x * sc * wb.x); o[5] = f2bf(b.y * sc * wb.y);
  o[6] = f2bf(b.z * sc * wb.z); o[7] = f2bf(b.w * sc * wb.w);
  *((u16x8*)(out + (size_t)row * D_MODEL) + t) = o;
}

// ============ 256x256 8-wave pipelined GEMM: C = A(MxK) @ Bt(NxK)^T =========
// 4 phases/K-tile; half-tile stream H_g (g=4t+p: A-k0,B-k0,A-k1,B-k1), issue
// lead 4 (all in-flight DMA targets the opposite buffer), counted vmcnt(6).
// T2 chunk-XOR swizzle kc = ch ^ ((row>>1)&3): linear DMA dest, pre-swizzled
// global source, swizzled ds_read (8 lanes/bank-quartet on b128 = optimal).
// EPI: 0 = bf16 out, 1 = f32 out + fp32 residual, 2 = silu -> bf16 out
#define GPHASE(T, P, VM, ISSUE)                                                \
  {                                                                            \
    if (ISSUE) issue_half(4 * (T) + (P) + 4);                                  \
    asm volatile("s_waitcnt vmcnt(" #VM ")" ::: "memory");                     \
    __builtin_amdgcn_sched_barrier(0);                                         \
    __builtin_amdgcn_s_barrier();                                              \
    if (((P) & 1) == 0) {                                                      \
      const u16* SA = S + (((((T) & 1) << 2) | (((P) >> 1) << 1)) << 13);      \
      const u16* SB = SA + 8192;                                               \
      _Pragma("unroll") for (int m = 0; m < 8; ++m) {                          \
        int row = wm * 128 + m * 16 + r16;                                     \
        aF[m] = *(const u16x8*)(SA + row * 32 + ((kg ^ ((row >> 1) & 3)) << 3)); \
      }                                                                        \
      _Pragma("unroll") for (int n = 0; n < 4; ++n) {                          \
        int row = wn * 64 + n * 16 + r16;                                      \
        bF[n] = *(const u16x8*)(SB + row * 32 + ((kg ^ ((row >> 1) & 3)) << 3)); \
      }                                                                        \
    }                                                                          \
    __builtin_amdgcn_s_setprio(1);                                             \
    _Pragma("unroll") for (int m = 0; m < 8; ++m) {                            \
      acc[m][2 * ((P) & 1)] = mfma16(aF[m], bF[2 * ((P) & 1)], acc[m][2 * ((P) & 1)]); \
      acc[m][2 * ((P) & 1) + 1] =                                              \
          mfma16(aF[m], bF[2 * ((P) & 1) + 1], acc[m][2 * ((P) & 1) + 1]);     \
    }                                                                          \
    __builtin_amdgcn_s_setprio(0);                                             \
    __builtin_amdgcn_s_barrier();                                              \
  }

template <int EPI>
__global__ __launch_bounds__(512, 1) void gemm256_kernel(
    const u16* __restrict__ A, const u16* __restrict__ Bt, void* __restrict__ Cv,
    const float* __restrict__ res, int N, int K) {
  __shared__ __align__(16) u16 S[8 * 8192];  // 8 x 16 KB half-regions = 128 KB
  const int tid = threadIdx.x, lane = tid & 63, wave = tid >> 6;
  const int wm = wave >> 2, wn = wave & 3;
  const int r16 = lane & 15, kg = lane >> 4;
  const int cols = N >> 8;
  const int cpx = gridDim.x >> 3;
  const int bid = blockIdx.x;
  const int swz = (bid & 7) * cpx + (bid >> 3);
  const int bm = (swz / cols) * 256, bn = (swz % cols) * 256;
  const int nt = K >> 6;

  auto issue_half = [&](int h) {
    int p = h & 3, t = h >> 2;
    const u16* src = (p & 1) ? (Bt + (size_t)bn * K) : (A + (size_t)bm * K);
    int kbase = t * 64 + (p >> 1) * 32;
    u16* ldst = S + ((((t & 1) << 2) | p) << 13);
#pragma unroll
    for (int i = 0; i < 2; ++i) {
      int c = i * 512 + tid;
      int row = c >> 2, ch = c & 3;
      int kc = ch ^ ((row >> 1) & 3);
      gll16(src + (size_t)row * K + kbase + kc * 8, ldst + c * 8);
    }
  };

  u16x8 aF[8], bF[4];
  f32x4 acc[8][4] = {};

  issue_half(0); issue_half(1); issue_half(2); issue_half(3);
  for (int t = 0; t < nt - 1; ++t) {
    GPHASE(t, 0, 6, true);
    GPHASE(t, 1, 6, true);
    GPHASE(t, 2, 6, true);
    GPHASE(t, 3, 6, true);
  }
  {
    const int t = nt - 1;
    GPHASE(t, 0, 4, false);
    GPHASE(t, 1, 4, false);
    GPHASE(t, 2, 0, false);
    GPHASE(t, 3, 0, false);
  }

#pragma unroll
  for (int m = 0; m < 8; ++m) {
    int r0 = bm + wm * 128 + m * 16 + kg * 4;
#pragma unroll
    for (int n = 0; n < 4; ++n) {
      int cc = bn + wn * 64 + n * 16 + r16;
#pragma unroll
      for (int r = 0; r < 4; ++r) {
        size_t idx = (size_t)(r0 + r) * N + cc;
        float v = acc[m][n][r];
        if (EPI == 1) {
          ((float*)Cv)[idx] = res[idx] + v;
        } else if (EPI == 0) {
          ((u16*)Cv)[idx] = f2bf(v);
        } else {
          float s = v / (1.0f + __expf(-v));
          ((u16*)Cv)[idx] = f2bf(s);
        }
      }
    }
  }
}

// ---------------- flash attention v2 (round-5, verified) --------------------
template <bool CAUSAL, bool SELF>
__global__ __launch_bounds__(512, 2) void attn2_kernel(
    const u16* __restrict__ qp, const u16* __restrict__ kp,
    const u16* __restrict__ vtp, u16* __restrict__ outp) {
  __shared__ __align__(16) u16 Kl[64 * 128];   // 16 KB
  __shared__ __align__(16) u16 Vl[128 * 64];   // 16 KB
  const int tid = threadIdx.x, lane = tid & 63, wave = tid >> 6;
  const int lo = lane & 31, hi = lane >> 5;
  const int qt = blockIdx.x, bh = blockIdx.y, b = bh >> 4, h = bh & 15;
  const int qw0 = qt * 256 + wave * 32;
  const int qg = qw0 + lo;
  const size_t qstr = SELF ? 6144 : 2048;
  const size_t kstr = SELF ? 6144 : 512;
  const u16* qbase = qp + ((size_t)b * SEQ + qg) * qstr + h * HD;
  const u16* kbase = kp + (size_t)b * SEQ * kstr + (SELF ? (2048 + h * HD) : ((h >> 2) * HD));
  const u16* vbase = vtp + (size_t)(SELF ? (b * NH + h) : (b * 4 + (h >> 2))) * HD * SEQ;

  u16x8 qf[8];
#pragma unroll
  for (int dc = 0; dc < 8; ++dc) qf[dc] = *(const u16x8*)(qbase + dc * 16 + hi * 8);

  f32x16 o[4] = {};
  float m_run = -3e38f, l_run = 0.f;
  const int ntiles = CAUSAL ? qt * 4 + 4 : SEQ / 64;
  const float scale = 0.088388347648318447f;  // 1/sqrt(128)

  for (int kt = 0; kt < ntiles; ++kt) {
    __syncthreads();
#pragma unroll
    for (int i = 0; i < 2; ++i) {
      int c = i * 512 + tid;
      int krow = c >> 4, ks = c & 15;
      gll16(kbase + (size_t)(kt * 64 + krow) * kstr + ((ks ^ (krow & 15)) * 8),
            Kl + (size_t)c * 8);
      int vd = c >> 3, vs = c & 7;
      gll16(vbase + (size_t)vd * SEQ + kt * 64 + ((vs ^ (vd & 7)) * 8),
            Vl + (size_t)c * 8);
    }
    __syncthreads();
    if (CAUSAL && kt * 64 > qw0 + 31) continue;

    f32x16 s01[2] = {};
#pragma unroll
    for (int k2 = 0; k2 < 2; ++k2) {
      int key = k2 * 32 + lo;
#pragma unroll
      for (int mf = 0; mf < 8; ++mf) {
        int dc = mf * 2 + hi;
        u16x8 kf = *(const u16x8*)(Kl + key * 128 + ((dc ^ (key & 15)) * 8));
        s01[k2] = mfma32(kf, qf[mf], s01[k2]);
      }
    }

    float sv[32];
    float pm = -3e38f;
#pragma unroll
    for (int k2 = 0; k2 < 2; ++k2)
#pragma unroll
      for (int r = 0; r < 16; ++r) {
        float v = s01[k2][r];
        if (CAUSAL) {
          int key = kt * 64 + k2 * 32 + (r & 3) + 8 * (r >> 2) + 4 * hi;
          if (key > qg) v = -3e38f;
        }
        sv[k2 * 16 + r] = v;
        pm = fmaxf(pm, v);
      }
    pm = fmaxf(pm, __shfl_xor(pm, 32, 64));
    float mn = fmaxf(m_run, pm);
    float corr = __expf((m_run - mn) * scale);
    m_run = mn;

    float ps = 0.f;
    u16x8 pf[4];
#pragma unroll
    for (int k2 = 0; k2 < 2; ++k2)
#pragma unroll
      for (int hf = 0; hf < 2; ++hf) {
        float p8[8];
#pragma unroll
        for (int j = 0; j < 8; ++j) {
          p8[j] = __expf((sv[k2 * 16 + hf * 8 + j] - mn) * scale);
          ps += p8[j];
        }
        unsigned w0, w1, w2, w3;
        asm("v_cvt_pk_bf16_f32 %0, %1, %2" : "=v"(w0) : "v"(p8[0]), "v"(p8[1]));
        asm("v_cvt_pk_bf16_f32 %0, %1, %2" : "=v"(w1) : "v"(p8[2]), "v"(p8[3]));
        asm("v_cvt_pk_bf16_f32 %0, %1, %2" : "=v"(w2) : "v"(p8[4]), "v"(p8[5]));
        asm("v_cvt_pk_bf16_f32 %0, %1, %2" : "=v"(w3) : "v"(p8[6]), "v"(p8[7]));
        asm("v_permlane32_swap_b32 %0, %1" : "+v"(w0), "+v"(w2));
        asm("v_permlane32_swap_b32 %0, %1" : "+v"(w1), "+v"(w3));
        u32x4 fr; fr[0] = w0; fr[1] = w1; fr[2] = w2; fr[3] = w3;
        pf[k2 * 2 + hf] = __builtin_bit_cast(u16x8, fr);
      }
    ps += __shfl_xor(ps, 32, 64);
    l_run = l_run * corr + ps;

#pragma unroll
    for (int mb = 0; mb < 4; ++mb)
#pragma unroll
      for (int r = 0; r < 16; ++r) o[mb][r] *= corr;

#pragma unroll
    for (int kc = 0; kc < 4; ++kc) {
      int vcs = kc * 2 + hi;
#pragma unroll
      for (int mb = 0; mb < 4; ++mb) {
        int d = mb * 32 + lo;
        u16x8 vf = *(const u16x8*)(Vl + d * 64 + ((vcs ^ (d & 7)) * 8));
        o[mb] = mfma32(vf, pf[kc], o[mb]);
      }
    }
  }

  float inv = 1.0f / l_run;
  u16* ob = outp + ((size_t)b * SEQ + qg) * D_MODEL + h * HD + 4 * hi;
#pragma unroll
  for (int mb = 0; mb < 4; ++mb)
#pragma unroll
    for (int rq = 0; rq < 4; ++rq) {
      u16x4 w;
#pragma unroll
      for (int j = 0; j < 4; ++j) w[j] = f2bf(o[mb][rq * 4 + j] * inv);
      *(u16x4*)(ob + mb * 32 + rq * 8) = w;
    }
}

extern "C" void kernel_launch(void* const* d_in, const int* in_sizes, int n_in,
                              void* d_out, int out_size, void* d_ws, size_t ws_size,
                              hipStream_t stream) {
  const float* x          = (const float*)d_in[0];
  const float* k_ctx      = (const float*)d_in[1];
  const float* v_ctx      = (const float*)d_in[2];
  const float* wq         = (const float*)d_in[3];
  const float* wo_cross   = (const float*)d_in[4];
  const float* norm_q_w   = (const float*)d_in[5];
  const float* wqkv       = (const float*)d_in[6];
  const float* wo_self    = (const float*)d_in[7];
  const float* norm_qkv_w = (const float*)d_in[8];
  const float* ffn_w1     = (const float*)d_in[9];
  const float* ffn_w2     = (const float*)d_in[10];
  const float* ffn_norm_w = (const float*)d_in[11];
  float* out = (float*)d_out;

  char* ws = (char*)d_ws;
  size_t off = 0;
  auto alloc_u16 = [&](size_t n) { u16* p = (u16*)(ws + off); off += n * 2; return p; };
  auto alloc_f32 = [&](size_t n) { float* p = (float*)(ws + off); off += n * 4; return p; };
  u16* wq_bf   = alloc_u16((size_t)2048 * 2048);   // [N][K]
  u16* woc_bf  = alloc_u16((size_t)2048 * 2048);
  u16* wqkv_bf = alloc_u16((size_t)2048 * 6144);
  u16* wos_bf  = alloc_u16((size_t)2048 * 2048);
  u16* w1_bf   = alloc_u16((size_t)2048 * 8192);
  u16* w2_bf   = alloc_u16((size_t)8192 * 2048);
  u16* xn_bf   = alloc_u16((size_t)ROWS * 2048);
  u16* qkv_bf  = alloc_u16((size_t)ROWS * 6144);
  u16* attn_bf = alloc_u16((size_t)ROWS * 2048);
  float* x1    = alloc_f32((size_t)ROWS * 2048);
  float* x2    = alloc_f32((size_t)ROWS * 2048);
  u16* q_bf    = qkv_bf;
  u16* h1_bf   = qkv_bf;                // qkv + attn regions hold FFN hidden
  u16* kc_bf   = (u16*)x2;              // x2 dead until self-attn out-GEMM
  u16* vt_ctx  = kc_bf + (size_t)BATCH * SEQ * 4 * HD;   // [b][g][128][SEQ]
  u16* vt_self = xn_bf;                 // xn dead between qkv-GEMM and FFN norm

  auto castT = [&](const float* src, u16* dst, int K, int N) {
    cast_transpose_kernel<<<dim3(N / 64, K / 64), 256, 0, stream>>>(src, dst, K, N);
  };
  castT(wq, wq_bf, 2048, 2048);
  castT(wo_cross, woc_bf, 2048, 2048);
  castT(wqkv, wqkv_bf, 2048, 6144);
  castT(wo_self, wos_bf, 2048, 2048);
  castT(ffn_w1, w1_bf, 2048, 8192);
  castT(ffn_w2, w2_bf, 8192, 2048);
  {
    int n8 = (int)((size_t)BATCH * SEQ * 4 * HD / 8);
    cast_kernel<<<dim3((n8 + 255) / 256), dim3(256), 0, stream>>>(k_ctx, kc_bf, n8);
  }
  build_vt_kernel<float><<<dim3(SEQ / 64, HD / 64, BATCH * 4), 256, 0, stream>>>(
      v_ctx, vt_ctx, 4, (size_t)SEQ * 512, (size_t)HD, 512);

  // ---- cross attention (GQA) ----
  rmsnorm_kernel<<<ROWS, 256, 0, stream>>>(x, norm_q_w, xn_bf);
  gemm256_kernel<0><<<dim3((ROWS / 256) * (2048 / 256)), 512, 0, stream>>>(
      xn_bf, wq_bf, q_bf, nullptr, 2048, 2048);
  attn2_kernel<false, false><<<dim3(SEQ / 256, BATCH * NH), 512, 0, stream>>>(
      q_bf, kc_bf, vt_ctx, attn_bf);
  gemm256_kernel<1><<<dim3((ROWS / 256) * (2048 / 256)), 512, 0, stream>>>(
      attn_bf, woc_bf, x1, x, 2048, 2048);

  // ---- causal self attention ----
  rmsnorm_kernel<<<ROWS, 256, 0, stream>>>(x1, norm_qkv_w, xn_bf);
  gemm256_kernel<0><<<dim3((ROWS / 256) * (6144 / 256)), 512, 0, stream>>>(
      xn_bf, wqkv_bf, qkv_bf, nullptr, 6144, 2048);
  build_vt_kernel<u16><<<dim3(SEQ / 64, HD / 64, BATCH * NH), 256, 0, stream>>>(
      qkv_bf + 4096, vt_self, NH, (size_t)SEQ * 6144, (size_t)HD, 6144);
  attn2_kernel<true, true><<<dim3(SEQ / 256, BATCH * NH), 512, 0, stream>>>(
      qkv_bf, qkv_bf, vt_self, attn_bf);
  gemm256_kernel<1><<<dim3((ROWS / 256) * (2048 / 256)), 512, 0, stream>>>(
      attn_bf, wos_bf, x2, x1, 2048, 2048);

  // ---- FFN (SiLU) ----
  rmsnorm_kernel<<<ROWS, 256, 0, stream>>>(x2, ffn_norm_w, xn_bf);
  gemm256_kernel<2><<<dim3((ROWS / 256) * (8192 / 256)), 512, 0, stream>>>(
      xn_bf, w1_bf, h1_bf, nullptr, 8192, 2048);
  gemm256_kernel<1><<<dim3((ROWS / 256) * (2048 / 256)), 512, 0, stream>>>(
      h1_bf, w2_bf, out, x2, 2048, 8192);
}

// Round 7
// 878.418 us; speedup vs baseline: 7.3842x; 1.0828x over previous
//
#include <hip/hip_runtime.h>
#include <math.h>

typedef unsigned short u16;
typedef __attribute__((ext_vector_type(4))) u16 u16x4;
typedef __attribute__((ext_vector_type(8))) u16 u16x8;
typedef __attribute__((ext_vector_type(8))) __bf16 bf16x8;
typedef __attribute__((ext_vector_type(4))) float f32x4;
typedef __attribute__((ext_vector_type(16))) float f32x16;
typedef __attribute__((ext_vector_type(4))) unsigned u32x4;

#define D_MODEL 2048
#define SEQ 2048
#define BATCH 2
#define NH 16
#define HD 128
#define DFF 8192
#define ROWS (BATCH * SEQ)  // 4096

__device__ __forceinline__ u16 f2bf(float f) {
  union { float f; unsigned u; } v; v.f = f;
  unsigned r = v.u + 0x7FFFu + ((v.u >> 16) & 1u);
  return (u16)(r >> 16);
}
__device__ __forceinline__ u16 to_bf16(float f) { return f2bf(f); }
__device__ __forceinline__ u16 to_bf16(u16 v) { return v; }

__device__ __forceinline__ f32x4 mfma16(u16x8 a, u16x8 b, f32x4 c) {
  return __builtin_amdgcn_mfma_f32_16x16x32_bf16(
      __builtin_bit_cast(bf16x8, a), __builtin_bit_cast(bf16x8, b), c, 0, 0, 0);
}
__device__ __forceinline__ f32x16 mfma32(u16x8 a, u16x8 b, f32x16 c) {
  return __builtin_amdgcn_mfma_f32_32x32x16_bf16(
      __builtin_bit_cast(bf16x8, a), __builtin_bit_cast(bf16x8, b), c, 0, 0, 0);
}

__device__ __forceinline__ void gll16(const void* g, void* l) {
  __builtin_amdgcn_global_load_lds(
      (const __attribute__((address_space(1))) void*)g,
      (__attribute__((address_space(3))) void*)l, 16, 0, 0);
}

// ---------------- fp32 -> bf16 bulk cast ----------------
__global__ __launch_bounds__(256) void cast_kernel(const float* __restrict__ in,
                                                   u16* __restrict__ out, int n8) {
  int i = blockIdx.x * 256 + threadIdx.x;
  if (i >= n8) return;
  const float4* p = (const float4*)in + (size_t)i * 2;
  float4 a = p[0], b = p[1];
  u16x8 o;
  o[0] = f2bf(a.x); o[1] = f2bf(a.y); o[2] = f2bf(a.z); o[3] = f2bf(a.w);
  o[4] = f2bf(b.x); o[5] = f2bf(b.y); o[6] = f2bf(b.z); o[7] = f2bf(b.w);
  *((u16x8*)out + i) = o;
}

// ---------------- fp32 [K][N] -> bf16 [N][K] transpose-cast (weights) -------
__global__ __launch_bounds__(256) void cast_transpose_kernel(
    const float* __restrict__ in, u16* __restrict__ out, int K, int N) {
  __shared__ float tile[64][65];
  int n0 = blockIdx.x * 64, k0 = blockIdx.y * 64;
  int tx = threadIdx.x & 63, ty = threadIdx.x >> 6;
#pragma unroll
  for (int i = 0; i < 64; i += 4)
    tile[ty + i][tx] = in[(size_t)(k0 + ty + i) * N + n0 + tx];
  __syncthreads();
#pragma unroll
  for (int i = 0; i < 64; i += 4)
    out[(size_t)(n0 + ty + i) * K + k0 + tx] = f2bf(tile[tx][ty + i]);
}

// ---------------- build V^T: per (b,zh): [SEQ][128] -> [128][SEQ] bf16 ------
template <typename ST>
__global__ __launch_bounds__(256) void build_vt_kernel(
    const ST* __restrict__ src, u16* __restrict__ dst, int HZ,
    size_t src_b_stride, size_t src_h_stride, int src_tok_stride) {
  __shared__ u16 tl[64][72];
  int z = blockIdx.z, zb = z / HZ, zh = z % HZ;
  const ST* s = src + (size_t)zb * src_b_stride + (size_t)zh * src_h_stride;
  int t0 = blockIdx.x * 64, d0 = blockIdx.y * 64;
  int rr = threadIdx.x >> 4, cc = (threadIdx.x & 15) * 4;
#pragma unroll
  for (int pp = 0; pp < 4; ++pp) {
    int t = pp * 16 + rr;
    const ST* sp = s + (size_t)(t0 + t) * src_tok_stride + d0 + cc;
#pragma unroll
    for (int j = 0; j < 4; ++j) tl[t][cc + j] = to_bf16(sp[j]);
  }
  __syncthreads();
  u16* dp = dst + (size_t)z * HD * SEQ;
#pragma unroll
  for (int pp = 0; pp < 4; ++pp) {
    int d = pp * 16 + rr;
    u16x4 w;
#pragma unroll
    for (int j = 0; j < 4; ++j) w[j] = tl[cc + j][d];
    *(u16x4*)(dp + (size_t)(d0 + d) * SEQ + t0 + cc) = w;
  }
}

// ---------------- RMSNorm (fp32 in, bf16 out) ----------------
__global__ __launch_bounds__(256) void rmsnorm_kernel(const float* __restrict__ x,
                                                      const float* __restrict__ w,
                                                      u16* __restrict__ out) {
  __shared__ float red[4];
  int row = blockIdx.x, t = threadIdx.x;
  const float4* xr = (const float4*)(x + (size_t)row * D_MODEL);
  float4 a = xr[t * 2], b = xr[t * 2 + 1];
  float ss = a.x * a.x + a.y * a.y + a.z * a.z + a.w * a.w +
             b.x * b.x + b.y * b.y + b.z * b.z + b.w * b.w;
#pragma unroll
  for (int m = 1; m < 64; m <<= 1) ss += __shfl_xor(ss, m, 64);
  if ((t & 63) == 0) red[t >> 6] = ss;
  __syncthreads();
  float tot = red[0] + red[1] + red[2] + red[3];
  float sc = rsqrtf(tot * (1.0f / D_MODEL) + 1e-6f);
  const float4* wr = (const float4*)w;
  float4 wa = wr[t * 2], wb = wr[t * 2 + 1];
  u16x8 o;
  o[0] = f2bf(a.x * sc * wa.x); o[1] = f2bf(a.y * sc * wa.y);
  o[2] = f2bf(a.z * sc * wa.z); o[3] = f2bf(a.w * sc * wa.w);
  o[4] = f2bf(b.x * sc * wb.x); o[5] = f2bf(b.y * sc * wb.y);
  o[6] = f2bf(b.z * sc * wb.z); o[7] = f2bf(b.w * sc * wb.w);
  *((u16x8*)(out + (size_t)row * D_MODEL) + t) = o;
}

// ---------------- split-K combine ----------------
// MODE 0: bf16 out = p0+p1 ; MODE 1: f32 out = res + p0 + p1
// (p0 may alias outv element-wise: each thread reads before writing.)
template <int MODE>
__global__ __launch_bounds__(256) void combine_kernel(
    const float* __restrict__ p0, const float* __restrict__ p1,
    const float* __restrict__ res, void* __restrict__ outv, int n4) {
  int i = blockIdx.x * 256 + threadIdx.x;
  if (i >= n4) return;
  float4 a = ((const float4*)p0)[i];
  float4 b = ((const float4*)p1)[i];
  if (MODE == 1) {
    float4 r = ((const float4*)res)[i];
    float4 o;
    o.x = r.x + a.x + b.x; o.y = r.y + a.y + b.y;
    o.z = r.z + a.z + b.z; o.w = r.w + a.w + b.w;
    ((float4*)outv)[i] = o;
  } else {
    u16x4 o;
    o[0] = f2bf(a.x + b.x); o[1] = f2bf(a.y + b.y);
    o[2] = f2bf(a.z + b.z); o[3] = f2bf(a.w + b.w);
    ((u16x4*)outv)[i] = o;
  }
}

// ============ 256x256 8-wave pipelined GEMM: C = A(MxK) @ Bt(NxK)^T =========
// Verified round-6 schedule. SPLIT=2: grid doubles, kslice = swz/tiles; each
// slice computes K/2 and writes f32 partial (EPI=3) to Cv (slice0) / Cv2 (1).
// EPI: 0 = bf16 out, 1 = f32 out + res, 2 = silu bf16, 3 = f32 partial.
#define GPHASE(T, P, VM, ISSUE)                                                \
  {                                                                            \
    if (ISSUE) issue_half(4 * (T) + (P) + 4);                                  \
    asm volatile("s_waitcnt vmcnt(" #VM ")" ::: "memory");                     \
    __builtin_amdgcn_sched_barrier(0);                                         \
    __builtin_amdgcn_s_barrier();                                              \
    if (((P) & 1) == 0) {                                                      \
      const u16* SA = S + (((((T) & 1) << 2) | (((P) >> 1) << 1)) << 13);      \
      const u16* SB = SA + 8192;                                               \
      _Pragma("unroll") for (int m = 0; m < 8; ++m) {                          \
        int row = wm * 128 + m * 16 + r16;                                     \
        aF[m] = *(const u16x8*)(SA + row * 32 + ((kg ^ ((row >> 1) & 3)) << 3)); \
      }                                                                        \
      _Pragma("unroll") for (int n = 0; n < 4; ++n) {                          \
        int row = wn * 64 + n * 16 + r16;                                      \
        bF[n] = *(const u16x8*)(SB + row * 32 + ((kg ^ ((row >> 1) & 3)) << 3)); \
      }                                                                        \
    }                                                                          \
    __builtin_amdgcn_s_setprio(1);                                             \
    _Pragma("unroll") for (int m = 0; m < 8; ++m) {                            \
      acc[m][2 * ((P) & 1)] = mfma16(aF[m], bF[2 * ((P) & 1)], acc[m][2 * ((P) & 1)]); \
      acc[m][2 * ((P) & 1) + 1] =                                              \
          mfma16(aF[m], bF[2 * ((P) & 1) + 1], acc[m][2 * ((P) & 1) + 1]);     \
    }                                                                          \
    __builtin_amdgcn_s_setprio(0);                                             \
    __builtin_amdgcn_s_barrier();                                              \
  }

template <int EPI, int SPLIT>
__global__ __launch_bounds__(512, 1) void gemm256_kernel(
    const u16* __restrict__ A, const u16* __restrict__ Bt, void* __restrict__ Cv,
    float* __restrict__ Cv2, const float* __restrict__ res, int N, int K) {
  __shared__ __align__(16) u16 S[8 * 8192];  // 8 x 16 KB half-regions = 128 KB
  const int tid = threadIdx.x, lane = tid & 63, wave = tid >> 6;
  const int wm = wave >> 2, wn = wave & 3;
  const int r16 = lane & 15, kg = lane >> 4;
  const int cols = N >> 8;
  const int cpx = gridDim.x >> 3;
  const int bid = blockIdx.x;
  const int swz = (bid & 7) * cpx + (bid >> 3);
  const int tiles = gridDim.x / SPLIT;
  const int tile = swz % tiles, kslice = swz / tiles;
  const int bm = (tile / cols) * 256, bn = (tile % cols) * 256;
  const int Ksub = K / SPLIT;
  const int koff = kslice * Ksub;
  const int nt = Ksub >> 6;

  auto issue_half = [&](int h) {
    int p = h & 3, t = h >> 2;
    const u16* src = (p & 1) ? (Bt + (size_t)bn * K) : (A + (size_t)bm * K);
    int kbase = koff + t * 64 + (p >> 1) * 32;
    u16* ldst = S + ((((t & 1) << 2) | p) << 13);
#pragma unroll
    for (int i = 0; i < 2; ++i) {
      int c = i * 512 + tid;
      int row = c >> 2, ch = c & 3;
      int kc = ch ^ ((row >> 1) & 3);
      gll16(src + (size_t)row * K + kbase + kc * 8, ldst + c * 8);
    }
  };

  u16x8 aF[8], bF[4];
  f32x4 acc[8][4] = {};

  issue_half(0); issue_half(1); issue_half(2); issue_half(3);
  for (int t = 0; t < nt - 1; ++t) {
    GPHASE(t, 0, 6, true);
    GPHASE(t, 1, 6, true);
    GPHASE(t, 2, 6, true);
    GPHASE(t, 3, 6, true);
  }
  {
    const int t = nt - 1;
    GPHASE(t, 0, 4, false);
    GPHASE(t, 1, 4, false);
    GPHASE(t, 2, 0, false);
    GPHASE(t, 3, 0, false);
  }

  float* Pp = (EPI == 3) ? (kslice ? Cv2 : (float*)Cv) : nullptr;
#pragma unroll
  for (int m = 0; m < 8; ++m) {
    int r0 = bm + wm * 128 + m * 16 + kg * 4;
#pragma unroll
    for (int n = 0; n < 4; ++n) {
      int cc = bn + wn * 64 + n * 16 + r16;
#pragma unroll
      for (int r = 0; r < 4; ++r) {
        size_t idx = (size_t)(r0 + r) * N + cc;
        float v = acc[m][n][r];
        if (EPI == 3) {
          Pp[idx] = v;
        } else if (EPI == 1) {
          ((float*)Cv)[idx] = res[idx] + v;
        } else if (EPI == 0) {
          ((u16*)Cv)[idx] = f2bf(v);
        } else {
          float s = v / (1.0f + __expf(-v));
          ((u16*)Cv)[idx] = f2bf(s);
        }
      }
    }
  }
}

// ---------------- flash attention v2 (round-5, verified) --------------------
template <bool CAUSAL, bool SELF>
__global__ __launch_bounds__(512, 2) void attn2_kernel(
    const u16* __restrict__ qp, const u16* __restrict__ kp,
    const u16* __restrict__ vtp, u16* __restrict__ outp) {
  __shared__ __align__(16) u16 Kl[64 * 128];   // 16 KB
  __shared__ __align__(16) u16 Vl[128 * 64];   // 16 KB
  const int tid = threadIdx.x, lane = tid & 63, wave = tid >> 6;
  const int lo = lane & 31, hi = lane >> 5;
  const int qt = blockIdx.x, bh = blockIdx.y, b = bh >> 4, h = bh & 15;
  const int qw0 = qt * 256 + wave * 32;
  const int qg = qw0 + lo;
  const size_t qstr = SELF ? 6144 : 2048;
  const size_t kstr = SELF ? 6144 : 512;
  const u16* qbase = qp + ((size_t)b * SEQ + qg) * qstr + h * HD;
  const u16* kbase = kp + (size_t)b * SEQ * kstr + (SELF ? (2048 + h * HD) : ((h >> 2) * HD));
  const u16* vbase = vtp + (size_t)(SELF ? (b * NH + h) : (b * 4 + (h >> 2))) * HD * SEQ;

  u16x8 qf[8];
#pragma unroll
  for (int dc = 0; dc < 8; ++dc) qf[dc] = *(const u16x8*)(qbase + dc * 16 + hi * 8);

  f32x16 o[4] = {};
  float m_run = -3e38f, l_run = 0.f;
  const int ntiles = CAUSAL ? qt * 4 + 4 : SEQ / 64;
  const float scale = 0.088388347648318447f;  // 1/sqrt(128)

  for (int kt = 0; kt < ntiles; ++kt) {
    __syncthreads();
#pragma unroll
    for (int i = 0; i < 2; ++i) {
      int c = i * 512 + tid;
      int krow = c >> 4, ks = c & 15;
      gll16(kbase + (size_t)(kt * 64 + krow) * kstr + ((ks ^ (krow & 15)) * 8),
            Kl + (size_t)c * 8);
      int vd = c >> 3, vs = c & 7;
      gll16(vbase + (size_t)vd * SEQ + kt * 64 + ((vs ^ (vd & 7)) * 8),
            Vl + (size_t)c * 8);
    }
    __syncthreads();
    if (CAUSAL && kt * 64 > qw0 + 31) continue;

    f32x16 s01[2] = {};
#pragma unroll
    for (int k2 = 0; k2 < 2; ++k2) {
      int key = k2 * 32 + lo;
#pragma unroll
      for (int mf = 0; mf < 8; ++mf) {
        int dc = mf * 2 + hi;
        u16x8 kf = *(const u16x8*)(Kl + key * 128 + ((dc ^ (key & 15)) * 8));
        s01[k2] = mfma32(kf, qf[mf], s01[k2]);
      }
    }

    float sv[32];
    float pm = -3e38f;
#pragma unroll
    for (int k2 = 0; k2 < 2; ++k2)
#pragma unroll
      for (int r = 0; r < 16; ++r) {
        float v = s01[k2][r];
        if (CAUSAL) {
          int key = kt * 64 + k2 * 32 + (r & 3) + 8 * (r >> 2) + 4 * hi;
          if (key > qg) v = -3e38f;
        }
        sv[k2 * 16 + r] = v;
        pm = fmaxf(pm, v);
      }
    pm = fmaxf(pm, __shfl_xor(pm, 32, 64));
    float mn = fmaxf(m_run, pm);
    float corr = __expf((m_run - mn) * scale);
    m_run = mn;

    float ps = 0.f;
    u16x8 pf[4];
#pragma unroll
    for (int k2 = 0; k2 < 2; ++k2)
#pragma unroll
      for (int hf = 0; hf < 2; ++hf) {
        float p8[8];
#pragma unroll
        for (int j = 0; j < 8; ++j) {
          p8[j] = __expf((sv[k2 * 16 + hf * 8 + j] - mn) * scale);
          ps += p8[j];
        }
        unsigned w0, w1, w2, w3;
        asm("v_cvt_pk_bf16_f32 %0, %1, %2" : "=v"(w0) : "v"(p8[0]), "v"(p8[1]));
        asm("v_cvt_pk_bf16_f32 %0, %1, %2" : "=v"(w1) : "v"(p8[2]), "v"(p8[3]));
        asm("v_cvt_pk_bf16_f32 %0, %1, %2" : "=v"(w2) : "v"(p8[4]), "v"(p8[5]));
        asm("v_cvt_pk_bf16_f32 %0, %1, %2" : "=v"(w3) : "v"(p8[6]), "v"(p8[7]));
        asm("v_permlane32_swap_b32 %0, %1" : "+v"(w0), "+v"(w2));
        asm("v_permlane32_swap_b32 %0, %1" : "+v"(w1), "+v"(w3));
        u32x4 fr; fr[0] = w0; fr[1] = w1; fr[2] = w2; fr[3] = w3;
        pf[k2 * 2 + hf] = __builtin_bit_cast(u16x8, fr);
      }
    ps += __shfl_xor(ps, 32, 64);
    l_run = l_run * corr + ps;

#pragma unroll
    for (int mb = 0; mb < 4; ++mb)
#pragma unroll
      for (int r = 0; r < 16; ++r) o[mb][r] *= corr;

#pragma unroll
    for (int kc = 0; kc < 4; ++kc) {
      int vcs = kc * 2 + hi;
#pragma unroll
      for (int mb = 0; mb < 4; ++mb) {
        int d = mb * 32 + lo;
        u16x8 vf = *(const u16x8*)(Vl + d * 64 + ((vcs ^ (d & 7)) * 8));
        o[mb] = mfma32(vf, pf[kc], o[mb]);
      }
    }
  }

  float inv = 1.0f / l_run;
  u16* ob = outp + ((size_t)b * SEQ + qg) * D_MODEL + h * HD + 4 * hi;
#pragma unroll
  for (int mb = 0; mb < 4; ++mb)
#pragma unroll
    for (int rq = 0; rq < 4; ++rq) {
      u16x4 w;
#pragma unroll
      for (int j = 0; j < 4; ++j) w[j] = f2bf(o[mb][rq * 4 + j] * inv);
      *(u16x4*)(ob + mb * 32 + rq * 8) = w;
    }
}

extern "C" void kernel_launch(void* const* d_in, const int* in_sizes, int n_in,
                              void* d_out, int out_size, void* d_ws, size_t ws_size,
                              hipStream_t stream) {
  const float* x          = (const float*)d_in[0];
  const float* k_ctx      = (const float*)d_in[1];
  const float* v_ctx      = (const float*)d_in[2];
  const float* wq         = (const float*)d_in[3];
  const float* wo_cross   = (const float*)d_in[4];
  const float* norm_q_w   = (const float*)d_in[5];
  const float* wqkv       = (const float*)d_in[6];
  const float* wo_self    = (const float*)d_in[7];
  const float* norm_qkv_w = (const float*)d_in[8];
  const float* ffn_w1     = (const float*)d_in[9];
  const float* ffn_w2     = (const float*)d_in[10];
  const float* ffn_norm_w = (const float*)d_in[11];
  float* out = (float*)d_out;

  char* ws = (char*)d_ws;
  size_t off = 0;
  auto alloc_u16 = [&](size_t n) { u16* p = (u16*)(ws + off); off += n * 2; return p; };
  auto alloc_f32 = [&](size_t n) { float* p = (float*)(ws + off); off += n * 4; return p; };
  u16* wq_bf   = alloc_u16((size_t)2048 * 2048);   // [N][K]
  u16* woc_bf  = alloc_u16((size_t)2048 * 2048);
  u16* wqkv_bf = alloc_u16((size_t)2048 * 6144);
  u16* wos_bf  = alloc_u16((size_t)2048 * 2048);
  u16* w1_bf   = alloc_u16((size_t)2048 * 8192);
  u16* w2_bf   = alloc_u16((size_t)8192 * 2048);
  u16* xn_bf   = alloc_u16((size_t)ROWS * 2048);
  u16* qkv_bf  = alloc_u16((size_t)ROWS * 6144);
  u16* attn_bf = alloc_u16((size_t)ROWS * 2048);
  float* x1    = alloc_f32((size_t)ROWS * 2048);
  float* x2    = alloc_f32((size_t)ROWS * 2048);
  u16* q_bf    = qkv_bf;
  u16* h1_bf   = qkv_bf;                // qkv + attn regions hold FFN hidden
  u16* kc_bf   = (u16*)x2;              // x2 dead until wos partial
  u16* vt_ctx  = kc_bf + (size_t)BATCH * SEQ * 4 * HD;   // [b][g][128][SEQ]
  u16* vt_self = xn_bf;                 // xn dead between qkv-GEMM and FFN norm
  // split-K partial regions (all dead at their use time; ledger in notes):
  float* Pq1  = (float*)((char*)qkv_bf + 16777216);  // qkv[16.8MB..50.3MB)
  float* Pqkv = (float*)qkv_bf;                      // full 33.5 MB fits in qkv
  const int n4 = ROWS * 2048 / 4;

  auto castT = [&](const float* src, u16* dst, int K, int N) {
    cast_transpose_kernel<<<dim3(N / 64, K / 64), 256, 0, stream>>>(src, dst, K, N);
  };
  castT(wq, wq_bf, 2048, 2048);
  castT(wo_cross, woc_bf, 2048, 2048);
  castT(wqkv, wqkv_bf, 2048, 6144);
  castT(wo_self, wos_bf, 2048, 2048);
  castT(ffn_w1, w1_bf, 2048, 8192);
  castT(ffn_w2, w2_bf, 8192, 2048);
  {
    int n8 = (int)((size_t)BATCH * SEQ * 4 * HD / 8);
    cast_kernel<<<dim3((n8 + 255) / 256), dim3(256), 0, stream>>>(k_ctx, kc_bf, n8);
  }
  build_vt_kernel<float><<<dim3(SEQ / 64, HD / 64, BATCH * 4), 256, 0, stream>>>(
      v_ctx, vt_ctx, 4, (size_t)SEQ * 512, (size_t)HD, 512);

  // ---- cross attention (GQA) ----
  rmsnorm_kernel<<<ROWS, 256, 0, stream>>>(x, norm_q_w, xn_bf);
  // wq GEMM split-K: P0 = x1 region (dead), P1 = qkv tail; combine -> q_bf
  gemm256_kernel<3, 2><<<dim3(256), 512, 0, stream>>>(
      xn_bf, wq_bf, x1, Pq1, nullptr, 2048, 2048);
  combine_kernel<0><<<dim3((n4 + 255) / 256), 256, 0, stream>>>(
      x1, Pq1, nullptr, q_bf, n4);
  attn2_kernel<false, false><<<dim3(SEQ / 256, BATCH * NH), 512, 0, stream>>>(
      q_bf, kc_bf, vt_ctx, attn_bf);
  // wo_cross split-K: P0 = x1 (aliases output, safe), P1 = qkv (q dead)
  gemm256_kernel<3, 2><<<dim3(256), 512, 0, stream>>>(
      attn_bf, woc_bf, x1, Pqkv, nullptr, 2048, 2048);
  combine_kernel<1><<<dim3((n4 + 255) / 256), 256, 0, stream>>>(
      x1, Pqkv, x, x1, n4);

  // ---- causal self attention ----
  rmsnorm_kernel<<<ROWS, 256, 0, stream>>>(x1, norm_qkv_w, xn_bf);
  gemm256_kernel<0, 1><<<dim3((ROWS / 256) * (6144 / 256)), 512, 0, stream>>>(
      xn_bf, wqkv_bf, qkv_bf, nullptr, nullptr, 6144, 2048);
  build_vt_kernel<u16><<<dim3(SEQ / 64, HD / 64, BATCH * NH), 256, 0, stream>>>(
      qkv_bf + 4096, vt_self, NH, (size_t)SEQ * 6144, (size_t)HD, 6144);
  attn2_kernel<true, true><<<dim3(SEQ / 256, BATCH * NH), 512, 0, stream>>>(
      qkv_bf, qkv_bf, vt_self, attn_bf);
  // wo_self split-K: P0 = x2 region (kc/vt dead; aliases output), P1 = qkv
  gemm256_kernel<3, 2><<<dim3(256), 512, 0, stream>>>(
      attn_bf, wos_bf, x2, Pqkv, nullptr, 2048, 2048);
  combine_kernel<1><<<dim3((n4 + 255) / 256), 256, 0, stream>>>(
      x2, Pqkv, x1, x2, n4);

  // ---- FFN (SiLU) ----
  rmsnorm_kernel<<<ROWS, 256, 0, stream>>>(x2, ffn_norm_w, xn_bf);
  gemm256_kernel<2, 1><<<dim3((ROWS / 256) * (8192 / 256)), 512, 0, stream>>>(
      xn_bf, w1_bf, h1_bf, nullptr, nullptr, 8192, 2048);
  // ffn_w2 split-K: P0 = out region (aliases output), P1 = x1 (dead)
  gemm256_kernel<3, 2><<<dim3(256), 512, 0, stream>>>(
      h1_bf, w2_bf, out, x1, nullptr, 2048, 8192);
  combine_kernel<1><<<dim3((n4 + 255) / 256), 256, 0, stream>>>(
      out, x1, x2, out, n4);
}

// Round 8
// 837.976 us; speedup vs baseline: 7.7406x; 1.0483x over previous
//
#include <hip/hip_runtime.h>
#include <math.h>

typedef unsigned short u16;
typedef __attribute__((ext_vector_type(4))) u16 u16x4;
typedef __attribute__((ext_vector_type(8))) u16 u16x8;
typedef __attribute__((ext_vector_type(8))) __bf16 bf16x8;
typedef __attribute__((ext_vector_type(4))) float f32x4;
typedef __attribute__((ext_vector_type(16))) float f32x16;
typedef __attribute__((ext_vector_type(4))) unsigned u32x4;

#define D_MODEL 2048
#define SEQ 2048
#define BATCH 2
#define NH 16
#define HD 128
#define DFF 8192
#define ROWS (BATCH * SEQ)  // 4096

__device__ __forceinline__ u16 f2bf(float f) {
  union { float f; unsigned u; } v; v.f = f;
  unsigned r = v.u + 0x7FFFu + ((v.u >> 16) & 1u);
  return (u16)(r >> 16);
}
__device__ __forceinline__ u16 to_bf16(float f) { return f2bf(f); }
__device__ __forceinline__ u16 to_bf16(u16 v) { return v; }

__device__ __forceinline__ f32x4 mfma16(u16x8 a, u16x8 b, f32x4 c) {
  return __builtin_amdgcn_mfma_f32_16x16x32_bf16(
      __builtin_bit_cast(bf16x8, a), __builtin_bit_cast(bf16x8, b), c, 0, 0, 0);
}
__device__ __forceinline__ f32x16 mfma32(u16x8 a, u16x8 b, f32x16 c) {
  return __builtin_amdgcn_mfma_f32_32x32x16_bf16(
      __builtin_bit_cast(bf16x8, a), __builtin_bit_cast(bf16x8, b), c, 0, 0, 0);
}

__device__ __forceinline__ void gll16(const void* g, void* l) {
  __builtin_amdgcn_global_load_lds(
      (const __attribute__((address_space(1))) void*)g,
      (__attribute__((address_space(3))) void*)l, 16, 0, 0);
}

// ---------------- fp32 -> bf16 bulk cast ----------------
__global__ __launch_bounds__(256) void cast_kernel(const float* __restrict__ in,
                                                   u16* __restrict__ out, int n8) {
  int i = blockIdx.x * 256 + threadIdx.x;
  if (i >= n8) return;
  const float4* p = (const float4*)in + (size_t)i * 2;
  float4 a = p[0], b = p[1];
  u16x8 o;
  o[0] = f2bf(a.x); o[1] = f2bf(a.y); o[2] = f2bf(a.z); o[3] = f2bf(a.w);
  o[4] = f2bf(b.x); o[5] = f2bf(b.y); o[6] = f2bf(b.z); o[7] = f2bf(b.w);
  *((u16x8*)out + i) = o;
}

// ---------------- fp32 [K][N] -> bf16 [N][K] transpose-cast (weights) -------
__global__ __launch_bounds__(256) void cast_transpose_kernel(
    const float* __restrict__ in, u16* __restrict__ out, int K, int N) {
  __shared__ float tile[64][65];
  int n0 = blockIdx.x * 64, k0 = blockIdx.y * 64;
  int tx = threadIdx.x & 63, ty = threadIdx.x >> 6;
#pragma unroll
  for (int i = 0; i < 64; i += 4)
    tile[ty + i][tx] = in[(size_t)(k0 + ty + i) * N + n0 + tx];
  __syncthreads();
#pragma unroll
  for (int i = 0; i < 64; i += 4)
    out[(size_t)(n0 + ty + i) * K + k0 + tx] = f2bf(tile[tx][ty + i]);
}

// ---------------- build V^T: per (b,zh): [SEQ][128] -> [128][SEQ] bf16 ------
template <typename ST>
__global__ __launch_bounds__(256) void build_vt_kernel(
    const ST* __restrict__ src, u16* __restrict__ dst, int HZ,
    size_t src_b_stride, size_t src_h_stride, int src_tok_stride) {
  __shared__ u16 tl[64][72];
  int z = blockIdx.z, zb = z / HZ, zh = z % HZ;
  const ST* s = src + (size_t)zb * src_b_stride + (size_t)zh * src_h_stride;
  int t0 = blockIdx.x * 64, d0 = blockIdx.y * 64;
  int rr = threadIdx.x >> 4, cc = (threadIdx.x & 15) * 4;
#pragma unroll
  for (int pp = 0; pp < 4; ++pp) {
    int t = pp * 16 + rr;
    const ST* sp = s + (size_t)(t0 + t) * src_tok_stride + d0 + cc;
#pragma unroll
    for (int j = 0; j < 4; ++j) tl[t][cc + j] = to_bf16(sp[j]);
  }
  __syncthreads();
  u16* dp = dst + (size_t)z * HD * SEQ;
#pragma unroll
  for (int pp = 0; pp < 4; ++pp) {
    int d = pp * 16 + rr;
    u16x4 w;
#pragma unroll
    for (int j = 0; j < 4; ++j) w[j] = tl[cc + j][d];
    *(u16x4*)(dp + (size_t)(d0 + d) * SEQ + t0 + cc) = w;
  }
}

// ---------------- RMSNorm (fp32 in, bf16 out) ----------------
__global__ __launch_bounds__(256) void rmsnorm_kernel(const float* __restrict__ x,
                                                      const float* __restrict__ w,
                                                      u16* __restrict__ out) {
  __shared__ float red[4];
  int row = blockIdx.x, t = threadIdx.x;
  const float4* xr = (const float4*)(x + (size_t)row * D_MODEL);
  float4 a = xr[t * 2], b = xr[t * 2 + 1];
  float ss = a.x * a.x + a.y * a.y + a.z * a.z + a.w * a.w +
             b.x * b.x + b.y * b.y + b.z * b.z + b.w * b.w;
#pragma unroll
  for (int m = 1; m < 64; m <<= 1) ss += __shfl_xor(ss, m, 64);
  if ((t & 63) == 0) red[t >> 6] = ss;
  __syncthreads();
  float tot = red[0] + red[1] + red[2] + red[3];
  float sc = rsqrtf(tot * (1.0f / D_MODEL) + 1e-6f);
  const float4* wr = (const float4*)w;
  float4 wa = wr[t * 2], wb = wr[t * 2 + 1];
  u16x8 o;
  o[0] = f2bf(a.x * sc * wa.x); o[1] = f2bf(a.y * sc * wa.y);
  o[2] = f2bf(a.z * sc * wa.z); o[3] = f2bf(a.w * sc * wa.w);
  o[4] = f2bf(b.x * sc * wb.x); o[5] = f2bf(b.y * sc * wb.y);
  o[6] = f2bf(b.z * sc * wb.z); o[7] = f2bf(b.w * sc * wb.w);
  *((u16x8*)(out + (size_t)row * D_MODEL) + t) = o;
}

// ---------------- split-K combine (only ffn_w2 now) ----------------
template <int MODE>
__global__ __launch_bounds__(256) void combine_kernel(
    const float* __restrict__ p0, const float* __restrict__ p1,
    const float* __restrict__ res, void* __restrict__ outv, int n4) {
  int i = blockIdx.x * 256 + threadIdx.x;
  if (i >= n4) return;
  float4 a = ((const float4*)p0)[i];
  float4 b = ((const float4*)p1)[i];
  if (MODE == 1) {
    float4 r = ((const float4*)res)[i];
    float4 o;
    o.x = r.x + a.x + b.x; o.y = r.y + a.y + b.y;
    o.z = r.z + a.z + b.z; o.w = r.w + a.w + b.w;
    ((float4*)outv)[i] = o;
  } else {
    u16x4 o;
    o[0] = f2bf(a.x + b.x); o[1] = f2bf(a.y + b.y);
    o[2] = f2bf(a.z + b.z); o[3] = f2bf(a.w + b.w);
    ((u16x4*)outv)[i] = o;
  }
}

// ============ 256x256 8-wave pipelined GEMM (verified round-6/7) ============
#define GPHASE(T, P, VM, ISSUE)                                                \
  {                                                                            \
    if (ISSUE) issue_half(4 * (T) + (P) + 4);                                  \
    asm volatile("s_waitcnt vmcnt(" #VM ")" ::: "memory");                     \
    __builtin_amdgcn_sched_barrier(0);                                         \
    __builtin_amdgcn_s_barrier();                                              \
    if (((P) & 1) == 0) {                                                      \
      const u16* SA = S + (((((T) & 1) << 2) | (((P) >> 1) << 1)) << 13);      \
      const u16* SB = SA + 8192;                                               \
      _Pragma("unroll") for (int m = 0; m < 8; ++m) {                          \
        int row = wm * 128 + m * 16 + r16;                                     \
        aF[m] = *(const u16x8*)(SA + row * 32 + ((kg ^ ((row >> 1) & 3)) << 3)); \
      }                                                                        \
      _Pragma("unroll") for (int n = 0; n < 4; ++n) {                          \
        int row = wn * 64 + n * 16 + r16;                                      \
        bF[n] = *(const u16x8*)(SB + row * 32 + ((kg ^ ((row >> 1) & 3)) << 3)); \
      }                                                                        \
    }                                                                          \
    __builtin_amdgcn_s_setprio(1);                                             \
    _Pragma("unroll") for (int m = 0; m < 8; ++m) {                            \
      acc[m][2 * ((P) & 1)] = mfma16(aF[m], bF[2 * ((P) & 1)], acc[m][2 * ((P) & 1)]); \
      acc[m][2 * ((P) & 1) + 1] =                                              \
          mfma16(aF[m], bF[2 * ((P) & 1) + 1], acc[m][2 * ((P) & 1) + 1]);     \
    }                                                                          \
    __builtin_amdgcn_s_setprio(0);                                             \
    __builtin_amdgcn_s_barrier();                                              \
  }

template <int EPI, int SPLIT>
__global__ __launch_bounds__(512, 1) void gemm256_kernel(
    const u16* __restrict__ A, const u16* __restrict__ Bt, void* __restrict__ Cv,
    float* __restrict__ Cv2, const float* __restrict__ res, int N, int K) {
  __shared__ __align__(16) u16 S[8 * 8192];
  const int tid = threadIdx.x, lane = tid & 63, wave = tid >> 6;
  const int wm = wave >> 2, wn = wave & 3;
  const int r16 = lane & 15, kg = lane >> 4;
  const int cols = N >> 8;
  const int cpx = gridDim.x >> 3;
  const int bid = blockIdx.x;
  const int swz = (bid & 7) * cpx + (bid >> 3);
  const int tiles = gridDim.x / SPLIT;
  const int tile = swz % tiles, kslice = swz / tiles;
  const int bm = (tile / cols) * 256, bn = (tile % cols) * 256;
  const int Ksub = K / SPLIT;
  const int koff = kslice * Ksub;
  const int nt = Ksub >> 6;

  auto issue_half = [&](int h) {
    int p = h & 3, t = h >> 2;
    const u16* src = (p & 1) ? (Bt + (size_t)bn * K) : (A + (size_t)bm * K);
    int kbase = koff + t * 64 + (p >> 1) * 32;
    u16* ldst = S + ((((t & 1) << 2) | p) << 13);
#pragma unroll
    for (int i = 0; i < 2; ++i) {
      int c = i * 512 + tid;
      int row = c >> 2, ch = c & 3;
      int kc = ch ^ ((row >> 1) & 3);
      gll16(src + (size_t)row * K + kbase + kc * 8, ldst + c * 8);
    }
  };

  u16x8 aF[8], bF[4];
  f32x4 acc[8][4] = {};

  issue_half(0); issue_half(1); issue_half(2); issue_half(3);
  for (int t = 0; t < nt - 1; ++t) {
    GPHASE(t, 0, 6, true);
    GPHASE(t, 1, 6, true);
    GPHASE(t, 2, 6, true);
    GPHASE(t, 3, 6, true);
  }
  {
    const int t = nt - 1;
    GPHASE(t, 0, 4, false);
    GPHASE(t, 1, 4, false);
    GPHASE(t, 2, 0, false);
    GPHASE(t, 3, 0, false);
  }

  float* Pp = (EPI == 3) ? (kslice ? Cv2 : (float*)Cv) : nullptr;
#pragma unroll
  for (int m = 0; m < 8; ++m) {
    int r0 = bm + wm * 128 + m * 16 + kg * 4;
#pragma unroll
    for (int n = 0; n < 4; ++n) {
      int cc = bn + wn * 64 + n * 16 + r16;
#pragma unroll
      for (int r = 0; r < 4; ++r) {
        size_t idx = (size_t)(r0 + r) * N + cc;
        float v = acc[m][n][r];
        if (EPI == 3) {
          Pp[idx] = v;
        } else if (EPI == 1) {
          ((float*)Cv)[idx] = res[idx] + v;
        } else if (EPI == 0) {
          ((u16*)Cv)[idx] = f2bf(v);
        } else {
          float s = v / (1.0f + __expf(-v));
          ((u16*)Cv)[idx] = f2bf(s);
        }
      }
    }
  }
}

// ============ 256x128 8-wave pipelined GEMM (no split, full-chip grids) =====
// Same verified skeleton, 2 phases/K-tile; pair = A-half(2 loads)+B-half(1);
// one K-tile = 6 loads in flight -> vmcnt(6); tail 3 -> 0. 4 regions x 24KB.
// Waves: wm in 0..3 (64-row slabs), wn in 0..1 (64-col slabs); acc[4][4].
#define NPHASE(T, P, VM, ISSUE)                                                \
  {                                                                            \
    if (ISSUE) issue_pair(2 * (T) + (P) + 2);                                  \
    asm volatile("s_waitcnt vmcnt(" #VM ")" ::: "memory");                     \
    __builtin_amdgcn_sched_barrier(0);                                         \
    __builtin_amdgcn_s_barrier();                                              \
    const u16* SA = S + ((((T) & 1) * 2 + (P)) * 12288);                       \
    const u16* SB = SA + 8192;                                                 \
    u16x8 aF[4], bF[4];                                                        \
    _Pragma("unroll") for (int m = 0; m < 4; ++m) {                            \
      int row = wm * 64 + m * 16 + r16;                                        \
      aF[m] = *(const u16x8*)(SA + row * 32 + ((kg ^ ((row >> 1) & 3)) << 3)); \
    }                                                                          \
    _Pragma("unroll") for (int n = 0; n < 4; ++n) {                            \
      int row = wn * 64 + n * 16 + r16;                                        \
      bF[n] = *(const u16x8*)(SB + row * 32 + ((kg ^ ((row >> 1) & 3)) << 3)); \
    }                                                                          \
    __builtin_amdgcn_s_setprio(1);                                             \
    _Pragma("unroll") for (int m = 0; m < 4; ++m)                              \
      _Pragma("unroll") for (int n = 0; n < 4; ++n)                            \
        acc[m][n] = mfma16(aF[m], bF[n], acc[m][n]);                           \
    __builtin_amdgcn_s_setprio(0);                                             \
    __builtin_amdgcn_s_barrier();                                              \
  }

template <int EPI>
__global__ __launch_bounds__(512, 1) void gemm_n128_kernel(
    const u16* __restrict__ A, const u16* __restrict__ Bt, void* __restrict__ Cv,
    const float* __restrict__ res, int N, int K) {
  __shared__ __align__(16) u16 S[4 * 12288];  // 4 regions x 24 KB = 96 KB
  const int tid = threadIdx.x, lane = tid & 63, wave = tid >> 6;
  const int wm = wave >> 1, wn = wave & 1;
  const int r16 = lane & 15, kg = lane >> 4;
  const int cols = N >> 7;
  const int cpx = gridDim.x >> 3;
  const int bid = blockIdx.x;
  const int swz = (bid & 7) * cpx + (bid >> 3);
  const int bm = (swz / cols) * 256, bn = (swz % cols) * 128;
  const int nt = K >> 6;

  auto issue_pair = [&](int g) {
    int p = g & 1, t = g >> 1;
    int kbase = t * 64 + p * 32;
    u16* reg = S + (((t & 1) * 2 + p) * 12288);
#pragma unroll
    for (int i = 0; i < 2; ++i) {  // A: 256 rows x 32k = 1024 chunks
      int c = i * 512 + tid;
      int row = c >> 2, ch = c & 3;
      int kc = ch ^ ((row >> 1) & 3);
      gll16(A + (size_t)(bm + row) * K + kbase + kc * 8, reg + c * 8);
    }
    {  // B: 128 rows x 32k = 512 chunks
      int row = tid >> 2, ch = tid & 3;
      int kc = ch ^ ((row >> 1) & 3);
      gll16(Bt + (size_t)(bn + row) * K + kbase + kc * 8, reg + 8192 + tid * 8);
    }
  };

  f32x4 acc[4][4] = {};

  issue_pair(0); issue_pair(1);
  for (int t = 0; t < nt - 1; ++t) {
    NPHASE(t, 0, 6, true);
    NPHASE(t, 1, 6, true);
  }
  {
    const int t = nt - 1;
    NPHASE(t, 0, 3, false);
    NPHASE(t, 1, 0, false);
  }

#pragma unroll
  for (int m = 0; m < 4; ++m) {
    int r0 = bm + wm * 64 + m * 16 + kg * 4;
#pragma unroll
    for (int n = 0; n < 4; ++n) {
      int cc = bn + wn * 64 + n * 16 + r16;
#pragma unroll
      for (int r = 0; r < 4; ++r) {
        size_t idx = (size_t)(r0 + r) * N + cc;
        float v = acc[m][n][r];
        if (EPI == 1) {
          ((float*)Cv)[idx] = res[idx] + v;
        } else if (EPI == 0) {
          ((u16*)Cv)[idx] = f2bf(v);
        } else {
          float s = v / (1.0f + __expf(-v));
          ((u16*)Cv)[idx] = f2bf(s);
        }
      }
    }
  }
}

// ---------------- flash attention v2 (round-5, verified) --------------------
template <bool CAUSAL, bool SELF>
__global__ __launch_bounds__(512, 2) void attn2_kernel(
    const u16* __restrict__ qp, const u16* __restrict__ kp,
    const u16* __restrict__ vtp, u16* __restrict__ outp) {
  __shared__ __align__(16) u16 Kl[64 * 128];   // 16 KB
  __shared__ __align__(16) u16 Vl[128 * 64];   // 16 KB
  const int tid = threadIdx.x, lane = tid & 63, wave = tid >> 6;
  const int lo = lane & 31, hi = lane >> 5;
  const int qt = blockIdx.x, bh = blockIdx.y, b = bh >> 4, h = bh & 15;
  const int qw0 = qt * 256 + wave * 32;
  const int qg = qw0 + lo;
  const size_t qstr = SELF ? 6144 : 2048;
  const size_t kstr = SELF ? 6144 : 512;
  const u16* qbase = qp + ((size_t)b * SEQ + qg) * qstr + h * HD;
  const u16* kbase = kp + (size_t)b * SEQ * kstr + (SELF ? (2048 + h * HD) : ((h >> 2) * HD));
  const u16* vbase = vtp + (size_t)(SELF ? (b * NH + h) : (b * 4 + (h >> 2))) * HD * SEQ;

  u16x8 qf[8];
#pragma unroll
  for (int dc = 0; dc < 8; ++dc) qf[dc] = *(const u16x8*)(qbase + dc * 16 + hi * 8);

  f32x16 o[4] = {};
  float m_run = -3e38f, l_run = 0.f;
  const int ntiles = CAUSAL ? qt * 4 + 4 : SEQ / 64;
  const float scale = 0.088388347648318447f;  // 1/sqrt(128)

  for (int kt = 0; kt < ntiles; ++kt) {
    __syncthreads();
#pragma unroll
    for (int i = 0; i < 2; ++i) {
      int c = i * 512 + tid;
      int krow = c >> 4, ks = c & 15;
      gll16(kbase + (size_t)(kt * 64 + krow) * kstr + ((ks ^ (krow & 15)) * 8),
            Kl + (size_t)c * 8);
      int vd = c >> 3, vs = c & 7;
      gll16(vbase + (size_t)vd * SEQ + kt * 64 + ((vs ^ (vd & 7)) * 8),
            Vl + (size_t)c * 8);
    }
    __syncthreads();
    if (CAUSAL && kt * 64 > qw0 + 31) continue;

    f32x16 s01[2] = {};
#pragma unroll
    for (int k2 = 0; k2 < 2; ++k2) {
      int key = k2 * 32 + lo;
#pragma unroll
      for (int mf = 0; mf < 8; ++mf) {
        int dc = mf * 2 + hi;
        u16x8 kf = *(const u16x8*)(Kl + key * 128 + ((dc ^ (key & 15)) * 8));
        s01[k2] = mfma32(kf, qf[mf], s01[k2]);
      }
    }

    float sv[32];
    float pm = -3e38f;
#pragma unroll
    for (int k2 = 0; k2 < 2; ++k2)
#pragma unroll
      for (int r = 0; r < 16; ++r) {
        float v = s01[k2][r];
        if (CAUSAL) {
          int key = kt * 64 + k2 * 32 + (r & 3) + 8 * (r >> 2) + 4 * hi;
          if (key > qg) v = -3e38f;
        }
        sv[k2 * 16 + r] = v;
        pm = fmaxf(pm, v);
      }
    pm = fmaxf(pm, __shfl_xor(pm, 32, 64));
    float mn = fmaxf(m_run, pm);
    float corr = __expf((m_run - mn) * scale);
    m_run = mn;

    float ps = 0.f;
    u16x8 pf[4];
#pragma unroll
    for (int k2 = 0; k2 < 2; ++k2)
#pragma unroll
      for (int hf = 0; hf < 2; ++hf) {
        float p8[8];
#pragma unroll
        for (int j = 0; j < 8; ++j) {
          p8[j] = __expf((sv[k2 * 16 + hf * 8 + j] - mn) * scale);
          ps += p8[j];
        }
        unsigned w0, w1, w2, w3;
        asm("v_cvt_pk_bf16_f32 %0, %1, %2" : "=v"(w0) : "v"(p8[0]), "v"(p8[1]));
        asm("v_cvt_pk_bf16_f32 %0, %1, %2" : "=v"(w1) : "v"(p8[2]), "v"(p8[3]));
        asm("v_cvt_pk_bf16_f32 %0, %1, %2" : "=v"(w2) : "v"(p8[4]), "v"(p8[5]));
        asm("v_cvt_pk_bf16_f32 %0, %1, %2" : "=v"(w3) : "v"(p8[6]), "v"(p8[7]));
        asm("v_permlane32_swap_b32 %0, %1" : "+v"(w0), "+v"(w2));
        asm("v_permlane32_swap_b32 %0, %1" : "+v"(w1), "+v"(w3));
        u32x4 fr; fr[0] = w0; fr[1] = w1; fr[2] = w2; fr[3] = w3;
        pf[k2 * 2 + hf] = __builtin_bit_cast(u16x8, fr);
      }
    ps += __shfl_xor(ps, 32, 64);
    l_run = l_run * corr + ps;

#pragma unroll
    for (int mb = 0; mb < 4; ++mb)
#pragma unroll
      for (int r = 0; r < 16; ++r) o[mb][r] *= corr;

#pragma unroll
    for (int kc = 0; kc < 4; ++kc) {
      int vcs = kc * 2 + hi;
#pragma unroll
      for (int mb = 0; mb < 4; ++mb) {
        int d = mb * 32 + lo;
        u16x8 vf = *(const u16x8*)(Vl + d * 64 + ((vcs ^ (d & 7)) * 8));
        o[mb] = mfma32(vf, pf[kc], o[mb]);
      }
    }
  }

  float inv = 1.0f / l_run;
  u16* ob = outp + ((size_t)b * SEQ + qg) * D_MODEL + h * HD + 4 * hi;
#pragma unroll
  for (int mb = 0; mb < 4; ++mb)
#pragma unroll
    for (int rq = 0; rq < 4; ++rq) {
      u16x4 w;
#pragma unroll
      for (int j = 0; j < 4; ++j) w[j] = f2bf(o[mb][rq * 4 + j] * inv);
      *(u16x4*)(ob + mb * 32 + rq * 8) = w;
    }
}

extern "C" void kernel_launch(void* const* d_in, const int* in_sizes, int n_in,
                              void* d_out, int out_size, void* d_ws, size_t ws_size,
                              hipStream_t stream) {
  const float* x          = (const float*)d_in[0];
  const float* k_ctx      = (const float*)d_in[1];
  const float* v_ctx      = (const float*)d_in[2];
  const float* wq         = (const float*)d_in[3];
  const float* wo_cross   = (const float*)d_in[4];
  const float* norm_q_w   = (const float*)d_in[5];
  const float* wqkv       = (const float*)d_in[6];
  const float* wo_self    = (const float*)d_in[7];
  const float* norm_qkv_w = (const float*)d_in[8];
  const float* ffn_w1     = (const float*)d_in[9];
  const float* ffn_w2     = (const float*)d_in[10];
  const float* ffn_norm_w = (const float*)d_in[11];
  float* out = (float*)d_out;

  char* ws = (char*)d_ws;
  size_t off = 0;
  auto alloc_u16 = [&](size_t n) { u16* p = (u16*)(ws + off); off += n * 2; return p; };
  auto alloc_f32 = [&](size_t n) { float* p = (float*)(ws + off); off += n * 4; return p; };
  u16* wq_bf   = alloc_u16((size_t)2048 * 2048);   // [N][K]
  u16* woc_bf  = alloc_u16((size_t)2048 * 2048);
  u16* wqkv_bf = alloc_u16((size_t)2048 * 6144);
  u16* wos_bf  = alloc_u16((size_t)2048 * 2048);
  u16* w1_bf   = alloc_u16((size_t)2048 * 8192);
  u16* w2_bf   = alloc_u16((size_t)8192 * 2048);
  u16* xn_bf   = alloc_u16((size_t)ROWS * 2048);
  u16* qkv_bf  = alloc_u16((size_t)ROWS * 6144);
  u16* attn_bf = alloc_u16((size_t)ROWS * 2048);
  float* x1    = alloc_f32((size_t)ROWS * 2048);
  float* x2    = alloc_f32((size_t)ROWS * 2048);
  u16* q_bf    = qkv_bf;
  u16* h1_bf   = qkv_bf;                // qkv + attn regions hold FFN hidden
  u16* kc_bf   = (u16*)x2;              // x2 dead until wos output
  u16* vt_ctx  = kc_bf + (size_t)BATCH * SEQ * 4 * HD;   // [b][g][128][SEQ]
  u16* vt_self = xn_bf;                 // xn dead between qkv-GEMM and FFN norm
  const int n4 = ROWS * 2048 / 4;

  auto castT = [&](const float* src, u16* dst, int K, int N) {
    cast_transpose_kernel<<<dim3(N / 64, K / 64), 256, 0, stream>>>(src, dst, K, N);
  };
  castT(wq, wq_bf, 2048, 2048);
  castT(wo_cross, woc_bf, 2048, 2048);
  castT(wqkv, wqkv_bf, 2048, 6144);
  castT(wo_self, wos_bf, 2048, 2048);
  castT(ffn_w1, w1_bf, 2048, 8192);
  castT(ffn_w2, w2_bf, 8192, 2048);
  {
    int n8 = (int)((size_t)BATCH * SEQ * 4 * HD / 8);
    cast_kernel<<<dim3((n8 + 255) / 256), dim3(256), 0, stream>>>(k_ctx, kc_bf, n8);
  }
  build_vt_kernel<float><<<dim3(SEQ / 64, HD / 64, BATCH * 4), 256, 0, stream>>>(
      v_ctx, vt_ctx, 4, (size_t)SEQ * 512, (size_t)HD, 512);

  // ---- cross attention (GQA) ----
  rmsnorm_kernel<<<ROWS, 256, 0, stream>>>(x, norm_q_w, xn_bf);
  gemm_n128_kernel<0><<<dim3((ROWS / 256) * (2048 / 128)), 512, 0, stream>>>(
      xn_bf, wq_bf, q_bf, nullptr, 2048, 2048);
  attn2_kernel<false, false><<<dim3(SEQ / 256, BATCH * NH), 512, 0, stream>>>(
      q_bf, kc_bf, vt_ctx, attn_bf);
  gemm_n128_kernel<1><<<dim3((ROWS / 256) * (2048 / 128)), 512, 0, stream>>>(
      attn_bf, woc_bf, x1, x, 2048, 2048);

  // ---- causal self attention ----
  rmsnorm_kernel<<<ROWS, 256, 0, stream>>>(x1, norm_qkv_w, xn_bf);
  gemm_n128_kernel<0><<<dim3((ROWS / 256) * (6144 / 128)), 512, 0, stream>>>(
      xn_bf, wqkv_bf, qkv_bf, nullptr, 6144, 2048);
  build_vt_kernel<u16><<<dim3(SEQ / 64, HD / 64, BATCH * NH), 256, 0, stream>>>(
      qkv_bf + 4096, vt_self, NH, (size_t)SEQ * 6144, (size_t)HD, 6144);
  attn2_kernel<true, true><<<dim3(SEQ / 256, BATCH * NH), 512, 0, stream>>>(
      qkv_bf, qkv_bf, vt_self, attn_bf);
  gemm_n128_kernel<1><<<dim3((ROWS / 256) * (2048 / 128)), 512, 0, stream>>>(
      attn_bf, wos_bf, x2, x1, 2048, 2048);

  // ---- FFN (SiLU) ----
  rmsnorm_kernel<<<ROWS, 256, 0, stream>>>(x2, ffn_norm_w, xn_bf);
  gemm256_kernel<2, 1><<<dim3((ROWS / 256) * (8192 / 256)), 512, 0, stream>>>(
      xn_bf, w1_bf, h1_bf, nullptr, nullptr, 8192, 2048);
  // ffn_w2 split-K: P0 = out region (aliases output), P1 = x1 (dead)
  gemm256_kernel<3, 2><<<dim3(256), 512, 0, stream>>>(
      h1_bf, w2_bf, out, x1, nullptr, 2048, 8192);
  combine_kernel<1><<<dim3((n4 + 255) / 256), 256, 0, stream>>>(
      out, x1, x2, out, n4);
}

// Round 9
// 829.533 us; speedup vs baseline: 7.8194x; 1.0102x over previous
//
#include <hip/hip_runtime.h>
#include <math.h>

typedef unsigned short u16;
typedef __attribute__((ext_vector_type(4))) u16 u16x4;
typedef __attribute__((ext_vector_type(8))) u16 u16x8;
typedef __attribute__((ext_vector_type(8))) __bf16 bf16x8;
typedef __attribute__((ext_vector_type(4))) float f32x4;
typedef __attribute__((ext_vector_type(16))) float f32x16;
typedef __attribute__((ext_vector_type(4))) unsigned u32x4;

#define D_MODEL 2048
#define SEQ 2048
#define BATCH 2
#define NH 16
#define HD 128
#define DFF 8192
#define ROWS (BATCH * SEQ)  // 4096

__device__ __forceinline__ u16 f2bf(float f) {
  union { float f; unsigned u; } v; v.f = f;
  unsigned r = v.u + 0x7FFFu + ((v.u >> 16) & 1u);
  return (u16)(r >> 16);
}
__device__ __forceinline__ u16 to_bf16(float f) { return f2bf(f); }
__device__ __forceinline__ u16 to_bf16(u16 v) { return v; }

__device__ __forceinline__ f32x4 mfma16(u16x8 a, u16x8 b, f32x4 c) {
  return __builtin_amdgcn_mfma_f32_16x16x32_bf16(
      __builtin_bit_cast(bf16x8, a), __builtin_bit_cast(bf16x8, b), c, 0, 0, 0);
}
__device__ __forceinline__ f32x16 mfma32(u16x8 a, u16x8 b, f32x16 c) {
  return __builtin_amdgcn_mfma_f32_32x32x16_bf16(
      __builtin_bit_cast(bf16x8, a), __builtin_bit_cast(bf16x8, b), c, 0, 0, 0);
}

__device__ __forceinline__ void gll16(const void* g, void* l) {
  __builtin_amdgcn_global_load_lds(
      (const __attribute__((address_space(1))) void*)g,
      (__attribute__((address_space(3))) void*)l, 16, 0, 0);
}

// ---------------- fp32 -> bf16 bulk cast ----------------
__global__ __launch_bounds__(256) void cast_kernel(const float* __restrict__ in,
                                                   u16* __restrict__ out, int n8) {
  int i = blockIdx.x * 256 + threadIdx.x;
  if (i >= n8) return;
  const float4* p = (const float4*)in + (size_t)i * 2;
  float4 a = p[0], b = p[1];
  u16x8 o;
  o[0] = f2bf(a.x); o[1] = f2bf(a.y); o[2] = f2bf(a.z); o[3] = f2bf(a.w);
  o[4] = f2bf(b.x); o[5] = f2bf(b.y); o[6] = f2bf(b.z); o[7] = f2bf(b.w);
  *((u16x8*)out + i) = o;
}

// ---------------- fp32 [K][N] -> bf16 [N][K] transpose-cast (weights) -------
__global__ __launch_bounds__(256) void cast_transpose_kernel(
    const float* __restrict__ in, u16* __restrict__ out, int K, int N) {
  __shared__ float tile[64][65];
  int n0 = blockIdx.x * 64, k0 = blockIdx.y * 64;
  int tx = threadIdx.x & 63, ty = threadIdx.x >> 6;
#pragma unroll
  for (int i = 0; i < 64; i += 4)
    tile[ty + i][tx] = in[(size_t)(k0 + ty + i) * N + n0 + tx];
  __syncthreads();
#pragma unroll
  for (int i = 0; i < 64; i += 4)
    out[(size_t)(n0 + ty + i) * K + k0 + tx] = f2bf(tile[tx][ty + i]);
}

// ---------------- build V^T (cross only): [SEQ][128] -> [128][SEQ] bf16 -----
template <typename ST>
__global__ __launch_bounds__(256) void build_vt_kernel(
    const ST* __restrict__ src, u16* __restrict__ dst, int HZ,
    size_t src_b_stride, size_t src_h_stride, int src_tok_stride) {
  __shared__ u16 tl[64][72];
  int z = blockIdx.z, zb = z / HZ, zh = z % HZ;
  const ST* s = src + (size_t)zb * src_b_stride + (size_t)zh * src_h_stride;
  int t0 = blockIdx.x * 64, d0 = blockIdx.y * 64;
  int rr = threadIdx.x >> 4, cc = (threadIdx.x & 15) * 4;
#pragma unroll
  for (int pp = 0; pp < 4; ++pp) {
    int t = pp * 16 + rr;
    const ST* sp = s + (size_t)(t0 + t) * src_tok_stride + d0 + cc;
#pragma unroll
    for (int j = 0; j < 4; ++j) tl[t][cc + j] = to_bf16(sp[j]);
  }
  __syncthreads();
  u16* dp = dst + (size_t)z * HD * SEQ;
#pragma unroll
  for (int pp = 0; pp < 4; ++pp) {
    int d = pp * 16 + rr;
    u16x4 w;
#pragma unroll
    for (int j = 0; j < 4; ++j) w[j] = tl[cc + j][d];
    *(u16x4*)(dp + (size_t)(d0 + d) * SEQ + t0 + cc) = w;
  }
}

// ---------------- RMSNorm (fp32 in, bf16 out) ----------------
__global__ __launch_bounds__(256) void rmsnorm_kernel(const float* __restrict__ x,
                                                      const float* __restrict__ w,
                                                      u16* __restrict__ out) {
  __shared__ float red[4];
  int row = blockIdx.x, t = threadIdx.x;
  const float4* xr = (const float4*)(x + (size_t)row * D_MODEL);
  float4 a = xr[t * 2], b = xr[t * 2 + 1];
  float ss = a.x * a.x + a.y * a.y + a.z * a.z + a.w * a.w +
             b.x * b.x + b.y * b.y + b.z * b.z + b.w * b.w;
#pragma unroll
  for (int m = 1; m < 64; m <<= 1) ss += __shfl_xor(ss, m, 64);
  if ((t & 63) == 0) red[t >> 6] = ss;
  __syncthreads();
  float tot = red[0] + red[1] + red[2] + red[3];
  float sc = rsqrtf(tot * (1.0f / D_MODEL) + 1e-6f);
  const float4* wr = (const float4*)w;
  float4 wa = wr[t * 2], wb = wr[t * 2 + 1];
  u16x8 o;
  o[0] = f2bf(a.x * sc * wa.x); o[1] = f2bf(a.y * sc * wa.y);
  o[2] = f2bf(a.z * sc * wa.z); o[3] = f2bf(a.w * sc * wa.w);
  o[4] = f2bf(b.x * sc * wb.x); o[5] = f2bf(b.y * sc * wb.y);
  o[6] = f2bf(b.z * sc * wb.z); o[7] = f2bf(b.w * sc * wb.w);
  *((u16x8*)(out + (size_t)row * D_MODEL) + t) = o;
}

// ---------------- split-K combine (only ffn_w2) ----------------
template <int MODE>
__global__ __launch_bounds__(256) void combine_kernel(
    const float* __restrict__ p0, const float* __restrict__ p1,
    const float* __restrict__ res, void* __restrict__ outv, int n4) {
  int i = blockIdx.x * 256 + threadIdx.x;
  if (i >= n4) return;
  float4 a = ((const float4*)p0)[i];
  float4 b = ((const float4*)p1)[i];
  if (MODE == 1) {
    float4 r = ((const float4*)res)[i];
    float4 o;
    o.x = r.x + a.x + b.x; o.y = r.y + a.y + b.y;
    o.z = r.z + a.z + b.z; o.w = r.w + a.w + b.w;
    ((float4*)outv)[i] = o;
  } else {
    u16x4 o;
    o[0] = f2bf(a.x + b.x); o[1] = f2bf(a.y + b.y);
    o[2] = f2bf(a.z + b.z); o[3] = f2bf(a.w + b.w);
    ((u16x4*)outv)[i] = o;
  }
}

// ============ 256x256 8-wave pipelined GEMM (verified round-6/7/8) ==========
#define GPHASE(T, P, VM, ISSUE)                                                \
  {                                                                            \
    if (ISSUE) issue_half(4 * (T) + (P) + 4);                                  \
    asm volatile("s_waitcnt vmcnt(" #VM ")" ::: "memory");                     \
    __builtin_amdgcn_sched_barrier(0);                                         \
    __builtin_amdgcn_s_barrier();                                              \
    if (((P) & 1) == 0) {                                                      \
      const u16* SA = S + (((((T) & 1) << 2) | (((P) >> 1) << 1)) << 13);      \
      const u16* SB = SA + 8192;                                               \
      _Pragma("unroll") for (int m = 0; m < 8; ++m) {                          \
        int row = wm * 128 + m * 16 + r16;                                     \
        aF[m] = *(const u16x8*)(SA + row * 32 + ((kg ^ ((row >> 1) & 3)) << 3)); \
      }                                                                        \
      _Pragma("unroll") for (int n = 0; n < 4; ++n) {                          \
        int row = wn * 64 + n * 16 + r16;                                      \
        bF[n] = *(const u16x8*)(SB + row * 32 + ((kg ^ ((row >> 1) & 3)) << 3)); \
      }                                                                        \
    }                                                                          \
    __builtin_amdgcn_s_setprio(1);                                             \
    _Pragma("unroll") for (int m = 0; m < 8; ++m) {                            \
      acc[m][2 * ((P) & 1)] = mfma16(aF[m], bF[2 * ((P) & 1)], acc[m][2 * ((P) & 1)]); \
      acc[m][2 * ((P) & 1) + 1] =                                              \
          mfma16(aF[m], bF[2 * ((P) & 1) + 1], acc[m][2 * ((P) & 1) + 1]);     \
    }                                                                          \
    __builtin_amdgcn_s_setprio(0);                                             \
    __builtin_amdgcn_s_barrier();                                              \
  }

template <int EPI, int SPLIT>
__global__ __launch_bounds__(512, 1) void gemm256_kernel(
    const u16* __restrict__ A, const u16* __restrict__ Bt, void* __restrict__ Cv,
    float* __restrict__ Cv2, const float* __restrict__ res, int N, int K) {
  __shared__ __align__(16) u16 S[8 * 8192];
  const int tid = threadIdx.x, lane = tid & 63, wave = tid >> 6;
  const int wm = wave >> 2, wn = wave & 3;
  const int r16 = lane & 15, kg = lane >> 4;
  const int cols = N >> 8;
  const int cpx = gridDim.x >> 3;
  const int bid = blockIdx.x;
  const int swz = (bid & 7) * cpx + (bid >> 3);
  const int tiles = gridDim.x / SPLIT;
  const int tile = swz % tiles, kslice = swz / tiles;
  const int bm = (tile / cols) * 256, bn = (tile % cols) * 256;
  const int Ksub = K / SPLIT;
  const int koff = kslice * Ksub;
  const int nt = Ksub >> 6;

  auto issue_half = [&](int h) {
    int p = h & 3, t = h >> 2;
    const u16* src = (p & 1) ? (Bt + (size_t)bn * K) : (A + (size_t)bm * K);
    int kbase = koff + t * 64 + (p >> 1) * 32;
    u16* ldst = S + ((((t & 1) << 2) | p) << 13);
#pragma unroll
    for (int i = 0; i < 2; ++i) {
      int c = i * 512 + tid;
      int row = c >> 2, ch = c & 3;
      int kc = ch ^ ((row >> 1) & 3);
      gll16(src + (size_t)row * K + kbase + kc * 8, ldst + c * 8);
    }
  };

  u16x8 aF[8], bF[4];
  f32x4 acc[8][4] = {};

  issue_half(0); issue_half(1); issue_half(2); issue_half(3);
  for (int t = 0; t < nt - 1; ++t) {
    GPHASE(t, 0, 6, true);
    GPHASE(t, 1, 6, true);
    GPHASE(t, 2, 6, true);
    GPHASE(t, 3, 6, true);
  }
  {
    const int t = nt - 1;
    GPHASE(t, 0, 4, false);
    GPHASE(t, 1, 4, false);
    GPHASE(t, 2, 0, false);
    GPHASE(t, 3, 0, false);
  }

  float* Pp = (EPI == 3) ? (kslice ? Cv2 : (float*)Cv) : nullptr;
#pragma unroll
  for (int m = 0; m < 8; ++m) {
    int r0 = bm + wm * 128 + m * 16 + kg * 4;
#pragma unroll
    for (int n = 0; n < 4; ++n) {
      int cc = bn + wn * 64 + n * 16 + r16;
#pragma unroll
      for (int r = 0; r < 4; ++r) {
        size_t idx = (size_t)(r0 + r) * N + cc;
        float v = acc[m][n][r];
        if (EPI == 3) {
          Pp[idx] = v;
        } else if (EPI == 1) {
          ((float*)Cv)[idx] = res[idx] + v;
        } else if (EPI == 0) {
          ((u16*)Cv)[idx] = f2bf(v);
        } else {
          float s = v / (1.0f + __expf(-v));
          ((u16*)Cv)[idx] = f2bf(s);
        }
      }
    }
  }
}

// ============ 256x128 GEMM, 2-region double-buffer, 2 blocks/CU =============
// Pair g = one K-tile half... pair = A-half(2 loads/thread)+B-half(1); region
// g&1 (24 KB each, 48 KB total). Issue pair g+1 during compute of g ->
// vmcnt(3); tail vmcnt(0). Frag maps & swizzle identical to verified n128.
// EPI: 0 = bf16 out, 1 = f32 out + res, 4 = qkv: bf16 out, V-cols -> vt^T.
#define NPH2(T, P, VM, ISSUE)                                                  \
  {                                                                            \
    if (ISSUE) issue_pair(2 * (T) + (P) + 1);                                  \
    asm volatile("s_waitcnt vmcnt(" #VM ")" ::: "memory");                     \
    __builtin_amdgcn_sched_barrier(0);                                         \
    __builtin_amdgcn_s_barrier();                                              \
    const u16* SA = S + (((2 * (T) + (P)) & 1) * 12288);                       \
    const u16* SB = SA + 8192;                                                 \
    u16x8 aF[4], bF[4];                                                        \
    _Pragma("unroll") for (int m = 0; m < 4; ++m) {                            \
      int row = wm * 64 + m * 16 + r16;                                        \
      aF[m] = *(const u16x8*)(SA + row * 32 + ((kg ^ ((row >> 1) & 3)) << 3)); \
    }                                                                          \
    _Pragma("unroll") for (int n = 0; n < 4; ++n) {                            \
      int row = wn * 64 + n * 16 + r16;                                        \
      bF[n] = *(const u16x8*)(SB + row * 32 + ((kg ^ ((row >> 1) & 3)) << 3)); \
    }                                                                          \
    __builtin_amdgcn_s_setprio(1);                                             \
    _Pragma("unroll") for (int m = 0; m < 4; ++m)                              \
      _Pragma("unroll") for (int n = 0; n < 4; ++n)                            \
        acc[m][n] = mfma16(aF[m], bF[n], acc[m][n]);                           \
    __builtin_amdgcn_s_setprio(0);                                             \
    __builtin_amdgcn_s_barrier();                                              \
  }

template <int EPI>
__global__ __launch_bounds__(512, 4) void gemm_n128_kernel(
    const u16* __restrict__ A, const u16* __restrict__ Bt, void* __restrict__ Cv,
    const float* __restrict__ res, u16* __restrict__ vt, int N, int K) {
  __shared__ __align__(16) u16 S[2 * 12288];  // 2 regions x 24 KB = 48 KB
  const int tid = threadIdx.x, lane = tid & 63, wave = tid >> 6;
  const int wm = wave >> 1, wn = wave & 1;
  const int r16 = lane & 15, kg = lane >> 4;
  const int cols = N >> 7;
  const int cpx = gridDim.x >> 3;
  const int bid = blockIdx.x;
  const int swz = (bid & 7) * cpx + (bid >> 3);
  const int bm = (swz / cols) * 256, bn = (swz % cols) * 128;
  const int nt = K >> 6;

  auto issue_pair = [&](int g) {
    int p = g & 1, t = g >> 1;
    int kbase = t * 64 + p * 32;
    u16* reg = S + ((g & 1) * 12288);
#pragma unroll
    for (int i = 0; i < 2; ++i) {  // A: 256 rows x 32k = 1024 chunks
      int c = i * 512 + tid;
      int row = c >> 2, ch = c & 3;
      int kc = ch ^ ((row >> 1) & 3);
      gll16(A + (size_t)(bm + row) * K + kbase + kc * 8, reg + c * 8);
    }
    {  // B: 128 rows x 32k = 512 chunks
      int row = tid >> 2, ch = tid & 3;
      int kc = ch ^ ((row >> 1) & 3);
      gll16(Bt + (size_t)(bn + row) * K + kbase + kc * 8, reg + 8192 + tid * 8);
    }
  };

  f32x4 acc[4][4] = {};

  issue_pair(0);
  for (int t = 0; t < nt - 1; ++t) {
    NPH2(t, 0, 3, true);
    NPH2(t, 1, 3, true);
  }
  NPH2(nt - 1, 0, 3, true);
  NPH2(nt - 1, 1, 0, false);

  const bool vmode = (EPI == 4) && (bn >= 4096);
#pragma unroll
  for (int m = 0; m < 4; ++m) {
    int r0 = bm + wm * 64 + m * 16 + kg * 4;
#pragma unroll
    for (int n = 0; n < 4; ++n) {
      int cc = bn + wn * 64 + n * 16 + r16;
      if (vmode) {
        // V columns: write transposed vt[(b*16+h)*128+d][token], 4 tokens/u16x4
        int c2 = cc - 4096;
        int z = (r0 >> 11) * NH + (c2 >> 7);
        int d = c2 & 127;
        int t0 = r0 & (SEQ - 1);
        u16x4 w;
#pragma unroll
        for (int r = 0; r < 4; ++r) w[r] = f2bf(acc[m][n][r]);
        *(u16x4*)(vt + ((size_t)z * HD + d) * SEQ + t0) = w;
      } else {
#pragma unroll
        for (int r = 0; r < 4; ++r) {
          size_t idx = (size_t)(r0 + r) * N + cc;
          float v = acc[m][n][r];
          if (EPI == 1) {
            ((float*)Cv)[idx] = res[idx] + v;
          } else {
            ((u16*)Cv)[idx] = f2bf(v);
          }
        }
      }
    }
  }
}

// ---------------- flash attention v2 (+ defer-max T13) ----------------------
template <bool CAUSAL, bool SELF>
__global__ __launch_bounds__(512, 2) void attn2_kernel(
    const u16* __restrict__ qp, const u16* __restrict__ kp,
    const u16* __restrict__ vtp, u16* __restrict__ outp) {
  __shared__ __align__(16) u16 Kl[64 * 128];   // 16 KB
  __shared__ __align__(16) u16 Vl[128 * 64];   // 16 KB
  const int tid = threadIdx.x, lane = tid & 63, wave = tid >> 6;
  const int lo = lane & 31, hi = lane >> 5;
  const int qt = blockIdx.x, bh = blockIdx.y, b = bh >> 4, h = bh & 15;
  const int qw0 = qt * 256 + wave * 32;
  const int qg = qw0 + lo;
  const size_t qstr = SELF ? 6144 : 2048;
  const size_t kstr = SELF ? 6144 : 512;
  const u16* qbase = qp + ((size_t)b * SEQ + qg) * qstr + h * HD;
  const u16* kbase = kp + (size_t)b * SEQ * kstr + (SELF ? (2048 + h * HD) : ((h >> 2) * HD));
  const u16* vbase = vtp + (size_t)(SELF ? (b * NH + h) : (b * 4 + (h >> 2))) * HD * SEQ;

  u16x8 qf[8];
#pragma unroll
  for (int dc = 0; dc < 8; ++dc) qf[dc] = *(const u16x8*)(qbase + dc * 16 + hi * 8);

  f32x16 o[4] = {};
  float m_run = -3e38f, l_run = 0.f;
  const int ntiles = CAUSAL ? qt * 4 + 4 : SEQ / 64;
  const float scale = 0.088388347648318447f;  // 1/sqrt(128)
  const float defer_thr = 90.50966799187809f; // 8 / scale

  for (int kt = 0; kt < ntiles; ++kt) {
    __syncthreads();
#pragma unroll
    for (int i = 0; i < 2; ++i) {
      int c = i * 512 + tid;
      int krow = c >> 4, ks = c & 15;
      gll16(kbase + (size_t)(kt * 64 + krow) * kstr + ((ks ^ (krow & 15)) * 8),
            Kl + (size_t)c * 8);
      int vd = c >> 3, vs = c & 7;
      gll16(vbase + (size_t)vd * SEQ + kt * 64 + ((vs ^ (vd & 7)) * 8),
            Vl + (size_t)c * 8);
    }
    __syncthreads();
    if (CAUSAL && kt * 64 > qw0 + 31) continue;

    f32x16 s01[2] = {};
#pragma unroll
    for (int k2 = 0; k2 < 2; ++k2) {
      int key = k2 * 32 + lo;
#pragma unroll
      for (int mf = 0; mf < 8; ++mf) {
        int dc = mf * 2 + hi;
        u16x8 kf = *(const u16x8*)(Kl + key * 128 + ((dc ^ (key & 15)) * 8));
        s01[k2] = mfma32(kf, qf[mf], s01[k2]);
      }
    }

    float sv[32];
    float pm = -3e38f;
#pragma unroll
    for (int k2 = 0; k2 < 2; ++k2)
#pragma unroll
      for (int r = 0; r < 16; ++r) {
        float v = s01[k2][r];
        if (CAUSAL) {
          int key = kt * 64 + k2 * 32 + (r & 3) + 8 * (r >> 2) + 4 * hi;
          if (key > qg) v = -3e38f;
        }
        sv[k2 * 16 + r] = v;
        pm = fmaxf(pm, v);
      }
    pm = fmaxf(pm, __shfl_xor(pm, 32, 64));

    // defer-max (T13): skip rescale when tile max is within e^8 of running max
    const bool defer = __all(pm - m_run <= defer_thr);
    float mn = defer ? m_run : fmaxf(m_run, pm);
    float corr = defer ? 1.0f : __expf((m_run - mn) * scale);
    m_run = mn;

    float ps = 0.f;
    u16x8 pf[4];
#pragma unroll
    for (int k2 = 0; k2 < 2; ++k2)
#pragma unroll
      for (int hf = 0; hf < 2; ++hf) {
        float p8[8];
#pragma unroll
        for (int j = 0; j < 8; ++j) {
          p8[j] = __expf((sv[k2 * 16 + hf * 8 + j] - mn) * scale);
          ps += p8[j];
        }
        unsigned w0, w1, w2, w3;
        asm("v_cvt_pk_bf16_f32 %0, %1, %2" : "=v"(w0) : "v"(p8[0]), "v"(p8[1]));
        asm("v_cvt_pk_bf16_f32 %0, %1, %2" : "=v"(w1) : "v"(p8[2]), "v"(p8[3]));
        asm("v_cvt_pk_bf16_f32 %0, %1, %2" : "=v"(w2) : "v"(p8[4]), "v"(p8[5]));
        asm("v_cvt_pk_bf16_f32 %0, %1, %2" : "=v"(w3) : "v"(p8[6]), "v"(p8[7]));
        asm("v_permlane32_swap_b32 %0, %1" : "+v"(w0), "+v"(w2));
        asm("v_permlane32_swap_b32 %0, %1" : "+v"(w1), "+v"(w3));
        u32x4 fr; fr[0] = w0; fr[1] = w1; fr[2] = w2; fr[3] = w3;
        pf[k2 * 2 + hf] = __builtin_bit_cast(u16x8, fr);
      }
    ps += __shfl_xor(ps, 32, 64);

    if (defer) {
      l_run += ps;
    } else {
      l_run = l_run * corr + ps;
#pragma unroll
      for (int mb = 0; mb < 4; ++mb)
#pragma unroll
        for (int r = 0; r < 16; ++r) o[mb][r] *= corr;
    }

#pragma unroll
    for (int kc = 0; kc < 4; ++kc) {
      int vcs = kc * 2 + hi;
#pragma unroll
      for (int mb = 0; mb < 4; ++mb) {
        int d = mb * 32 + lo;
        u16x8 vf = *(const u16x8*)(Vl + d * 64 + ((vcs ^ (d & 7)) * 8));
        o[mb] = mfma32(vf, pf[kc], o[mb]);
      }
    }
  }

  float inv = 1.0f / l_run;
  u16* ob = outp + ((size_t)b * SEQ + qg) * D_MODEL + h * HD + 4 * hi;
#pragma unroll
  for (int mb = 0; mb < 4; ++mb)
#pragma unroll
    for (int rq = 0; rq < 4; ++rq) {
      u16x4 w;
#pragma unroll
      for (int j = 0; j < 4; ++j) w[j] = f2bf(o[mb][rq * 4 + j] * inv);
      *(u16x4*)(ob + mb * 32 + rq * 8) = w;
    }
}

extern "C" void kernel_launch(void* const* d_in, const int* in_sizes, int n_in,
                              void* d_out, int out_size, void* d_ws, size_t ws_size,
                              hipStream_t stream) {
  const float* x          = (const float*)d_in[0];
  const float* k_ctx      = (const float*)d_in[1];
  const float* v_ctx      = (const float*)d_in[2];
  const float* wq         = (const float*)d_in[3];
  const float* wo_cross   = (const float*)d_in[4];
  const float* norm_q_w   = (const float*)d_in[5];
  const float* wqkv       = (const float*)d_in[6];
  const float* wo_self    = (const float*)d_in[7];
  const float* norm_qkv_w = (const float*)d_in[8];
  const float* ffn_w1     = (const float*)d_in[9];
  const float* ffn_w2     = (const float*)d_in[10];
  const float* ffn_norm_w = (const float*)d_in[11];
  float* out = (float*)d_out;

  char* ws = (char*)d_ws;
  size_t off = 0;
  auto alloc_u16 = [&](size_t n) { u16* p = (u16*)(ws + off); off += n * 2; return p; };
  auto alloc_f32 = [&](size_t n) { float* p = (float*)(ws + off); off += n * 4; return p; };
  u16* wq_bf   = alloc_u16((size_t)2048 * 2048);   // [N][K]
  u16* woc_bf  = alloc_u16((size_t)2048 * 2048);
  u16* wqkv_bf = alloc_u16((size_t)2048 * 6144);
  u16* wos_bf  = alloc_u16((size_t)2048 * 2048);
  u16* w1_bf   = alloc_u16((size_t)2048 * 8192);
  u16* w2_bf   = alloc_u16((size_t)8192 * 2048);
  u16* xn_bf   = alloc_u16((size_t)ROWS * 2048);
  u16* qkv_bf  = alloc_u16((size_t)ROWS * 6144);
  u16* attn_bf = alloc_u16((size_t)ROWS * 2048);
  float* x1    = alloc_f32((size_t)ROWS * 2048);
  float* x2    = alloc_f32((size_t)ROWS * 2048);
  u16* q_bf    = qkv_bf;
  u16* h1_bf   = qkv_bf;                // qkv + attn regions hold FFN hidden
  u16* kc_bf   = (u16*)x2;              // x2 dead until wos output
  u16* vt_ctx  = kc_bf + (size_t)BATCH * SEQ * 4 * HD;   // [b][g][128][SEQ]
  // vt_self also lives in x2 (kc/vt_ctx dead after cross-attn; wos writes x2
  // only after self-attn consumed vt_self). NOT xn (qkv GEMM reads xn as A).
  u16* vt_self = (u16*)x2;
  const int n4 = ROWS * 2048 / 4;

  auto castT = [&](const float* src, u16* dst, int K, int N) {
    cast_transpose_kernel<<<dim3(N / 64, K / 64), 256, 0, stream>>>(src, dst, K, N);
  };
  castT(wq, wq_bf, 2048, 2048);
  castT(wo_cross, woc_bf, 2048, 2048);
  castT(wqkv, wqkv_bf, 2048, 6144);
  castT(wo_self, wos_bf, 2048, 2048);
  castT(ffn_w1, w1_bf, 2048, 8192);
  castT(ffn_w2, w2_bf, 8192, 2048);
  {
    int n8 = (int)((size_t)BATCH * SEQ * 4 * HD / 8);
    cast_kernel<<<dim3((n8 + 255) / 256), dim3(256), 0, stream>>>(k_ctx, kc_bf, n8);
  }
  build_vt_kernel<float><<<dim3(SEQ / 64, HD / 64, BATCH * 4), 256, 0, stream>>>(
      v_ctx, vt_ctx, 4, (size_t)SEQ * 512, (size_t)HD, 512);

  // ---- cross attention (GQA) ----
  rmsnorm_kernel<<<ROWS, 256, 0, stream>>>(x, norm_q_w, xn_bf);
  gemm_n128_kernel<0><<<dim3((ROWS / 256) * (2048 / 128)), 512, 0, stream>>>(
      xn_bf, wq_bf, q_bf, nullptr, nullptr, 2048, 2048);
  attn2_kernel<false, false><<<dim3(SEQ / 256, BATCH * NH), 512, 0, stream>>>(
      q_bf, kc_bf, vt_ctx, attn_bf);
  gemm_n128_kernel<1><<<dim3((ROWS / 256) * (2048 / 128)), 512, 0, stream>>>(
      attn_bf, woc_bf, x1, x, nullptr, 2048, 2048);

  // ---- causal self attention ----
  rmsnorm_kernel<<<ROWS, 256, 0, stream>>>(x1, norm_qkv_w, xn_bf);
  // qkv GEMM: q/k columns -> qkv_bf rows; V columns -> vt_self transposed
  gemm_n128_kernel<4><<<dim3((ROWS / 256) * (6144 / 128)), 512, 0, stream>>>(
      xn_bf, wqkv_bf, qkv_bf, nullptr, vt_self, 6144, 2048);
  attn2_kernel<true, true><<<dim3(SEQ / 256, BATCH * NH), 512, 0, stream>>>(
      qkv_bf, qkv_bf, vt_self, attn_bf);
  gemm_n128_kernel<1><<<dim3((ROWS / 256) * (2048 / 128)), 512, 0, stream>>>(
      attn_bf, wos_bf, x2, x1, nullptr, 2048, 2048);

  // ---- FFN (SiLU) ----
  rmsnorm_kernel<<<ROWS, 256, 0, stream>>>(x2, ffn_norm_w, xn_bf);
  gemm256_kernel<2, 1><<<dim3((ROWS / 256) * (8192 / 256)), 512, 0, stream>>>(
      xn_bf, w1_bf, h1_bf, nullptr, nullptr, 8192, 2048);
  // ffn_w2 split-K: P0 = out region (aliases output), P1 = x1 (dead)
  gemm256_kernel<3, 2><<<dim3(256), 512, 0, stream>>>(
      h1_bf, w2_bf, out, x1, nullptr, 2048, 8192);
  combine_kernel<1><<<dim3((n4 + 255) / 256), 256, 0, stream>>>(
      out, x1, x2, out, n4);
}